// Round 15
// baseline (435.289 us; speedup 1.0000x reference)
//
#include <hip/hip_runtime.h>
#include <math.h>

#define H 128
#define OUTD 40
#define BN_EPS 1e-5f
#define NEG_SLOPE 0.01f
#define RBITS 14
#define RSIZE 16384
#define NB 128           // edge chunks per range
#define NXCD 8

typedef __attribute__((ext_vector_type(8))) short bh8;
typedef __attribute__((ext_vector_type(4))) float f4;
typedef unsigned short u16;
typedef unsigned int u32;

__device__ __forceinline__ float4 ld4(const float* p) {
    return *reinterpret_cast<const float4*>(p);
}
__device__ __forceinline__ u16 f2bf(float f) {
    unsigned int u = __float_as_uint(f);
    u += 0x7fffu + ((u >> 16) & 1u);          // RNE
    return (u16)(u >> 16);
}
__device__ __forceinline__ float bflo(unsigned d) { return __uint_as_float(d << 16); }
__device__ __forceinline__ float bfhi(unsigned d) { return __uint_as_float(d & 0xffff0000u); }
__device__ __forceinline__ unsigned pk(float a, float b) {
    return (unsigned)f2bf(a) | ((unsigned)f2bf(b) << 16);
}
__device__ __forceinline__ int swz(int row, int byteInRow) {
    return row * 256 + (byteInRow ^ ((row & 7) << 4));
}

// ================= x -> bf16 =================
__global__ __launch_bounds__(256) void k_xbf(
    const float* __restrict__ x, u16* __restrict__ xb, int total8)
{
    int i = blockIdx.x * 256 + threadIdx.x;
    if (i >= total8) return;
    float4 a = ld4(x + (size_t)i * 8);
    float4 b = ld4(x + (size_t)i * 8 + 4);
    uint4 o;
    o.x = pk(a.x, a.y); o.y = pk(a.z, a.w);
    o.z = pk(b.x, b.y); o.w = pk(b.z, b.w);
    *reinterpret_cast<uint4*>(xb + (size_t)i * 8) = o;
}

// ================= weight prep: WT[c][k] = bf16(W[k][c]) =================
__global__ __launch_bounds__(256) void k_prep(
    const float* __restrict__ w1, const float* __restrict__ w2,
    const float* __restrict__ wl, const float* __restrict__ wr,
    u16* __restrict__ wt1, u16* __restrict__ wt2,
    u16* __restrict__ wtl, u16* __restrict__ wtr)
{
    int id = blockIdx.x * 256 + threadIdx.x;
    int sel = id >> 14;
    int o = id & 16383;
    int c = o >> 7, k = o & 127;
    const float* w = (sel == 0) ? w1 : (sel == 1) ? w2 : (sel == 2) ? wl : wr;
    u16* wt = (sel == 0) ? wt1 : (sel == 1) ? wt2 : (sel == 2) ? wtl : wtr;
    wt[o] = f2bf(w[k * H + c]);
}

// ================= CSR build (atomic-free, XCD-pinned) =================
__global__ __launch_bounds__(256) void k_hist2(
    const int* __restrict__ dst, u32* __restrict__ partial, int E, int nrange)
{
    __shared__ u32 hcnt[RSIZE / 2];
    const int tid = threadIdx.x;
    const int r = blockIdx.x & (NXCD - 1), bb = blockIdx.x >> 3;
    if (r >= nrange) return;
    for (int t = tid; t < RSIZE / 2; t += 256) hcnt[t] = 0;
    __syncthreads();
    const int lo = r << RBITS;
    const int chunk = (E + NB - 1) / NB;
    const int s0 = bb * chunk;
    const int s1 = min(E, s0 + chunk);
    for (int e = s0 + tid; e < s1; e += 256) {
        unsigned local = (unsigned)(dst[e] - lo);
        if (local < (unsigned)RSIZE)
            atomicAdd(&hcnt[local >> 1], 1u << ((local & 1) << 4));
    }
    __syncthreads();
    u32* out = partial + ((size_t)(r * NB + bb) << 13);
    for (int t = tid; t < RSIZE / 2; t += 256) out[t] = hcnt[t];
}

__global__ __launch_bounds__(256) void k_scan1(
    u32* __restrict__ partial, int* __restrict__ deg,
    int* __restrict__ cursor, int* __restrict__ bsum, int n)
{
    __shared__ int sums[256];
    const int tid = threadIdx.x;
    const int idx = blockIdx.x * 1024 + tid * 4;
    const int r = idx >> RBITS;
    const int jw = (idx & (RSIZE - 1)) >> 1;
    uint2 acc = {0u, 0u};
    for (int bb = 0; bb < NB; bb++) {
        u32* p = partial + (((size_t)(r * NB + bb)) << 13) + jw;
        uint2 w = *reinterpret_cast<uint2*>(p);
        *reinterpret_cast<uint2*>(p) = acc;
        acc.x += w.x; acc.y += w.y;
    }
    int4 v;
    v.x = (int)(acc.x & 0xFFFFu); v.y = (int)(acc.x >> 16);
    v.z = (int)(acc.y & 0xFFFFu); v.w = (int)(acc.y >> 16);
    if (idx + 0 >= n) v.x = 0;
    if (idx + 1 >= n) v.y = 0;
    if (idx + 2 >= n) v.z = 0;
    if (idx + 3 >= n) v.w = 0;
    if (idx + 3 < n) *reinterpret_cast<int4*>(deg + idx) = v;
    else {
        if (idx + 0 < n) deg[idx + 0] = v.x;
        if (idx + 1 < n) deg[idx + 1] = v.y;
        if (idx + 2 < n) deg[idx + 2] = v.z;
        if (idx + 3 < n) deg[idx + 3] = v.w;
    }
    int t = v.x + v.y + v.z + v.w;
    sums[tid] = t;
    __syncthreads();
    for (int off = 1; off < 256; off <<= 1) {
        int other = (tid >= off) ? sums[tid - off] : 0;
        __syncthreads();
        sums[tid] += other;
        __syncthreads();
    }
    int incl = sums[tid];
    int excl = incl - t;
    if (tid == 255) bsum[blockIdx.x] = incl;
    int c0 = excl, c1 = c0 + v.x, c2 = c1 + v.y, c3 = c2 + v.z;
    if (idx + 3 < n) {
        int4 o = {c0, c1, c2, c3};
        *reinterpret_cast<int4*>(cursor + idx) = o;
    } else {
        if (idx + 0 < n) cursor[idx + 0] = c0;
        if (idx + 1 < n) cursor[idx + 1] = c1;
        if (idx + 2 < n) cursor[idx + 2] = c2;
        if (idx + 3 < n) cursor[idx + 3] = c3;
    }
}

__global__ void k_scan2(int* __restrict__ bsum, int nb)
{
    __shared__ int s[1024];
    const int tid = threadIdx.x;
    for (int i = tid; i < nb; i += blockDim.x) s[i] = bsum[i];
    __syncthreads();
    if (tid == 0) {
        int acc = 0;
        for (int i = 0; i < nb; i++) { int t = s[i]; s[i] = acc; acc += t; }
    }
    __syncthreads();
    for (int i = tid; i < nb; i += blockDim.x) bsum[i] = s[i];
}

__global__ __launch_bounds__(256) void k_scan3(
    int* __restrict__ cursor, const int* __restrict__ bsum,
    const int* __restrict__ deg, float* __restrict__ dinv, int n)
{
    int i = blockIdx.x * 256 + threadIdx.x;
    if (i < n) {
        cursor[i] += bsum[i >> 10];
        dinv[i] = rsqrtf((float)deg[i] + 1.0f);
    }
}

__global__ __launch_bounds__(256) void k_fill2(
    const int* __restrict__ src, const int* __restrict__ dst,
    const int* __restrict__ cursor, const u32* __restrict__ partial,
    int* __restrict__ csr, int E, int nrange)
{
    __shared__ u32 rcnt[RSIZE / 2];
    const int tid = threadIdx.x;
    const int r = blockIdx.x & (NXCD - 1), bb = blockIdx.x >> 3;
    if (r >= nrange) return;
    for (int t = tid; t < RSIZE / 2; t += 256) rcnt[t] = 0;
    __syncthreads();
    const int lo = r << RBITS;
    const int chunk = (E + NB - 1) / NB;
    const int s0 = bb * chunk;
    const int s1 = min(E, s0 + chunk);
    const u32* pref = partial + ((size_t)(r * NB + bb) << 13);
    for (int e = s0 + tid; e < s1; e += 256) {
        int d = dst[e];
        unsigned local = (unsigned)(d - lo);
        if (local < (unsigned)RSIZE) {
            unsigned sh = (local & 1) << 4;
            unsigned old = atomicAdd(&rcnt[local >> 1], 1u << sh);
            unsigned rank = (old >> sh) & 0xFFFFu;
            unsigned pfx = (pref[local >> 1] >> sh) & 0xFFFFu;
            csr[cursor[d] + (int)pfx + (int)rank] = src[e];
        }
    }
}

// ================= gather aggregations (bf16 features) =================
__global__ __launch_bounds__(256) void k_agg1(
    const u16* __restrict__ xb, const int* __restrict__ csr,
    const int* __restrict__ cursor, const int* __restrict__ deg,
    u16* __restrict__ out, int n)
{
    int wave = (blockIdx.x * 256 + threadIdx.x) >> 6;
    int lane = threadIdx.x & 63;
    int row = wave * 4 + (lane >> 4);
    if (row >= n) return;
    int g = lane & 15;
    int start = cursor[row];
    int end = start + deg[row];
    float acc[8] = {0.f, 0.f, 0.f, 0.f, 0.f, 0.f, 0.f, 0.f};
    int i = start;
    for (; i + 4 <= end; i += 4) {
        int s0 = csr[i], s1 = csr[i + 1], s2 = csr[i + 2], s3 = csr[i + 3];
        uint4 a = *reinterpret_cast<const uint4*>(xb + (size_t)s0 * H + g * 8);
        uint4 b = *reinterpret_cast<const uint4*>(xb + (size_t)s1 * H + g * 8);
        uint4 c = *reinterpret_cast<const uint4*>(xb + (size_t)s2 * H + g * 8);
        uint4 d = *reinterpret_cast<const uint4*>(xb + (size_t)s3 * H + g * 8);
        acc[0] += (bflo(a.x) + bflo(b.x)) + (bflo(c.x) + bflo(d.x));
        acc[1] += (bfhi(a.x) + bfhi(b.x)) + (bfhi(c.x) + bfhi(d.x));
        acc[2] += (bflo(a.y) + bflo(b.y)) + (bflo(c.y) + bflo(d.y));
        acc[3] += (bfhi(a.y) + bfhi(b.y)) + (bfhi(c.y) + bfhi(d.y));
        acc[4] += (bflo(a.z) + bflo(b.z)) + (bflo(c.z) + bflo(d.z));
        acc[5] += (bfhi(a.z) + bfhi(b.z)) + (bfhi(c.z) + bfhi(d.z));
        acc[6] += (bflo(a.w) + bflo(b.w)) + (bflo(c.w) + bflo(d.w));
        acc[7] += (bfhi(a.w) + bfhi(b.w)) + (bfhi(c.w) + bfhi(d.w));
    }
    for (; i < end; i++) {
        int s = csr[i];
        uint4 a = *reinterpret_cast<const uint4*>(xb + (size_t)s * H + g * 8);
        acc[0] += bflo(a.x); acc[1] += bfhi(a.x);
        acc[2] += bflo(a.y); acc[3] += bfhi(a.y);
        acc[4] += bflo(a.z); acc[5] += bfhi(a.z);
        acc[6] += bflo(a.w); acc[7] += bfhi(a.w);
    }
    uint4 o;
    o.x = pk(acc[0], acc[1]); o.y = pk(acc[2], acc[3]);
    o.z = pk(acc[4], acc[5]); o.w = pk(acc[6], acc[7]);
    *reinterpret_cast<uint4*>(out + (size_t)row * H + g * 8) = o;
}

// act1h = bf16(relu(affine1(h))), elementwise
__global__ __launch_bounds__(256) void k_act1(
    const u16* __restrict__ hb, const float* __restrict__ scale, const float* __restrict__ shift,
    u16* __restrict__ out, int total8)
{
    int i = blockIdx.x * 256 + threadIdx.x;
    if (i >= total8) return;
    int g = i & 15;
    uint4 a = *reinterpret_cast<const uint4*>(hb + (size_t)i * 8);
    float4 sc0 = ld4(scale + g * 8), sc1 = ld4(scale + g * 8 + 4);
    float4 sh0 = ld4(shift + g * 8), sh1 = ld4(shift + g * 8 + 4);
    float e0 = fmaxf(bflo(a.x) * sc0.x + sh0.x, 0.f);
    float e1 = fmaxf(bfhi(a.x) * sc0.y + sh0.y, 0.f);
    float e2 = fmaxf(bflo(a.y) * sc0.z + sh0.z, 0.f);
    float e3 = fmaxf(bfhi(a.y) * sc0.w + sh0.w, 0.f);
    float e4 = fmaxf(bflo(a.z) * sc1.x + sh1.x, 0.f);
    float e5 = fmaxf(bfhi(a.z) * sc1.y + sh1.y, 0.f);
    float e6 = fmaxf(bflo(a.w) * sc1.z + sh1.z, 0.f);
    float e7 = fmaxf(bfhi(a.w) * sc1.w + sh1.w, 0.f);
    uint4 o;
    o.x = pk(e0, e1); o.y = pk(e2, e3); o.z = pk(e4, e5); o.w = pk(e6, e7);
    *reinterpret_cast<uint4*>(out + (size_t)i * 8) = o;
}

__global__ __launch_bounds__(256) void k_agg2(
    const u16* __restrict__ ab, const int* __restrict__ csr,
    const int* __restrict__ cursor, const int* __restrict__ deg,
    u16* __restrict__ out, int n)
{
    int wave = (blockIdx.x * 256 + threadIdx.x) >> 6;
    int lane = threadIdx.x & 63;
    int row = wave * 4 + (lane >> 4);
    if (row >= n) return;
    int g = lane & 15;
    int dg = deg[row];
    int start = cursor[row];
    int end = start + dg;
    float acc[8] = {0.f, 0.f, 0.f, 0.f, 0.f, 0.f, 0.f, 0.f};
    int i = start;
    for (; i + 4 <= end; i += 4) {
        int s0 = csr[i], s1 = csr[i + 1], s2 = csr[i + 2], s3 = csr[i + 3];
        uint4 a = *reinterpret_cast<const uint4*>(ab + (size_t)s0 * H + g * 8);
        uint4 b = *reinterpret_cast<const uint4*>(ab + (size_t)s1 * H + g * 8);
        uint4 c = *reinterpret_cast<const uint4*>(ab + (size_t)s2 * H + g * 8);
        uint4 d = *reinterpret_cast<const uint4*>(ab + (size_t)s3 * H + g * 8);
        acc[0] += (bflo(a.x) + bflo(b.x)) + (bflo(c.x) + bflo(d.x));
        acc[1] += (bfhi(a.x) + bfhi(b.x)) + (bfhi(c.x) + bfhi(d.x));
        acc[2] += (bflo(a.y) + bflo(b.y)) + (bflo(c.y) + bflo(d.y));
        acc[3] += (bfhi(a.y) + bfhi(b.y)) + (bfhi(c.y) + bfhi(d.y));
        acc[4] += (bflo(a.z) + bflo(b.z)) + (bflo(c.z) + bflo(d.z));
        acc[5] += (bfhi(a.z) + bfhi(b.z)) + (bfhi(c.z) + bfhi(d.z));
        acc[6] += (bflo(a.w) + bflo(b.w)) + (bflo(c.w) + bflo(d.w));
        acc[7] += (bfhi(a.w) + bfhi(b.w)) + (bfhi(c.w) + bfhi(d.w));
    }
    for (; i < end; i++) {
        int s = csr[i];
        uint4 a = *reinterpret_cast<const uint4*>(ab + (size_t)s * H + g * 8);
        acc[0] += bflo(a.x); acc[1] += bfhi(a.x);
        acc[2] += bflo(a.y); acc[3] += bfhi(a.y);
        acc[4] += bflo(a.z); acc[5] += bfhi(a.z);
        acc[6] += bflo(a.w); acc[7] += bfhi(a.w);
    }
    float idv = 1.0f / fmaxf((float)dg, 1.0f);
    uint4 o;
    o.x = pk(acc[0] * idv, acc[1] * idv); o.y = pk(acc[2] * idv, acc[3] * idv);
    o.z = pk(acc[4] * idv, acc[5] * idv); o.w = pk(acc[6] * idv, acc[7] * idv);
    *reinterpret_cast<uint4*>(out + (size_t)row * H + g * 8) = o;
}

// GCN gather + self-loop + bias + log-softmax; xws split: lo[N][32] (64B rows,
// 1 aligned line per read) + hi[N][8] (1.6MB, L2-resident). 8-deep ILP.
__global__ __launch_bounds__(256) void k_agg3(
    const u16* __restrict__ xlo, const u16* __restrict__ xhi,
    const float* __restrict__ dinv,
    const int* __restrict__ csr, const int* __restrict__ cursor, const int* __restrict__ deg,
    const float* __restrict__ bias, float* __restrict__ outp, int n)
{
    int wid = (blockIdx.x * 256 + threadIdx.x) >> 6;
    int lane = threadIdx.x & 63;
    if (wid >= n) return;
    int start = cursor[wid];
    int end = start + deg[wid];
    bool act = lane < OUTD;
    const u16* bp;
    int stride;
    if (lane < 32)      { bp = xlo + lane;        stride = 32; }
    else if (lane < 40) { bp = xhi + (lane - 32); stride = 8;  }
    else                { bp = xlo;               stride = 0;  }
    float acc = 0.f;
    int i = start;
    for (; i + 8 <= end; i += 8) {
        int s0 = csr[i], s1 = csr[i + 1], s2 = csr[i + 2], s3 = csr[i + 3];
        int s4 = csr[i + 4], s5 = csr[i + 5], s6 = csr[i + 6], s7 = csr[i + 7];
        float a0 = bflo(bp[(size_t)s0 * stride]);
        float a1 = bflo(bp[(size_t)s1 * stride]);
        float a2 = bflo(bp[(size_t)s2 * stride]);
        float a3 = bflo(bp[(size_t)s3 * stride]);
        float a4 = bflo(bp[(size_t)s4 * stride]);
        float a5 = bflo(bp[(size_t)s5 * stride]);
        float a6 = bflo(bp[(size_t)s6 * stride]);
        float a7 = bflo(bp[(size_t)s7 * stride]);
        acc += ((a0 + a1) + (a2 + a3)) + ((a4 + a5) + (a6 + a7));
    }
    for (; i + 2 <= end; i += 2) {
        int s0 = csr[i], s1 = csr[i + 1];
        acc += bflo(bp[(size_t)s0 * stride]) + bflo(bp[(size_t)s1 * stride]);
    }
    for (; i < end; i++) {
        acc += bflo(bp[(size_t)csr[i] * stride]);
    }
    float di = dinv[wid];
    float bc = act ? bias[lane] : 0.f;
    float v = di * (acc + bflo(bp[(size_t)wid * stride])) + bc;
    float m = act ? v : -INFINITY;
#pragma unroll
    for (int s = 1; s < 64; s <<= 1) m = fmaxf(m, __shfl_xor(m, s, 64));
    float ex = act ? expf(v - m) : 0.f;
    float sum = ex;
#pragma unroll
    for (int s = 1; s < 64; s <<= 1) sum += __shfl_xor(sum, s, 64);
    float l = logf(sum);
    if (act) outp[(size_t)wid * OUTD + lane] = v - m - l;
}

// ================= MFMA dense layers (128-row tiles, 512 threads) =================
__global__ __launch_bounds__(512) void k_gemm_film(
    const u16* __restrict__ A, const u16* __restrict__ W1T, const float* __restrict__ b1,
    const u16* __restrict__ W2T, const float* __restrict__ b2,
    u16* __restrict__ out, float* __restrict__ gsum, float* __restrict__ gsumsq, int n)
{
    __shared__ u16 sA[128 * 128];
    __shared__ u16 sB[128 * 128];
    __shared__ float cs[128], css[128];
    const int tid = threadIdx.x;
    const int rb = blockIdx.x * 128;
    if (tid < 128) { cs[tid] = 0.f; css[tid] = 0.f; }
    const int w = tid >> 6, l15 = tid & 15, grp = (tid & 63) >> 4;

#pragma unroll
    for (int j = 0; j < 4; j++) {
        int f = j * 512 + tid;
        int r = f >> 4, g = f & 15;
        int row = rb + r;
        uint4 v = {0, 0, 0, 0};
        if (row < n) v = *reinterpret_cast<const uint4*>(A + (size_t)row * H + g * 8);
        *reinterpret_cast<uint4*>((char*)sA + swz(r, g * 16)) = v;
    }
#pragma unroll
    for (int j = 0; j < 4; j++) {
        int f = j * 512 + tid;
        int r = f >> 4, kb = f & 15;
        uint4 v = *reinterpret_cast<const uint4*>(W1T + r * H + kb * 8);
        *reinterpret_cast<uint4*>((char*)sB + swz(r, kb * 16)) = v;
    }
    __syncthreads();
    f4 acc[8] = {};
#pragma unroll
    for (int kc = 0; kc < 4; kc++) {
        bh8 af = *reinterpret_cast<const bh8*>((char*)sA + swz(w * 16 + l15, kc * 64 + grp * 16));
#pragma unroll
        for (int nf = 0; nf < 8; nf++) {
            bh8 bv = *reinterpret_cast<const bh8*>((char*)sB + swz(nf * 16 + l15, kc * 64 + grp * 16));
            acc[nf] = __builtin_amdgcn_mfma_f32_16x16x32_bf16(af, bv, acc[nf], 0, 0, 0);
        }
    }
    __syncthreads();

#pragma unroll
    for (int nf = 0; nf < 8; nf++) {
        int col = nf * 16 + l15;
        float bc = b1[col];
#pragma unroll
        for (int j = 0; j < 4; j++) {
            int row = w * 16 + grp * 4 + j;
            float u = acc[nf][j] + bc;
            u = u > 0.f ? u : NEG_SLOPE * u;
            *reinterpret_cast<u16*>((char*)sA + swz(row, col * 2)) = f2bf(u);
        }
        acc[nf] = f4{0.f, 0.f, 0.f, 0.f};
    }
#pragma unroll
    for (int j = 0; j < 4; j++) {
        int f = j * 512 + tid;
        int r = f >> 4, kb = f & 15;
        uint4 v = *reinterpret_cast<const uint4*>(W2T + r * H + kb * 8);
        *reinterpret_cast<uint4*>((char*)sB + swz(r, kb * 16)) = v;
    }
    __syncthreads();

#pragma unroll
    for (int kc = 0; kc < 4; kc++) {
        bh8 af = *reinterpret_cast<const bh8*>((char*)sA + swz(w * 16 + l15, kc * 64 + grp * 16));
#pragma unroll
        for (int nf = 0; nf < 8; nf++) {
            bh8 bv = *reinterpret_cast<const bh8*>((char*)sB + swz(nf * 16 + l15, kc * 64 + grp * 16));
            acc[nf] = __builtin_amdgcn_mfma_f32_16x16x32_bf16(af, bv, acc[nf], 0, 0, 0);
        }
    }

#pragma unroll
    for (int nf = 0; nf < 8; nf++) {
        float bc = b2[nf * 16 + l15];
#pragma unroll
        for (int j = 0; j < 4; j++) acc[nf][j] += bc;
    }
    float inv[4];
#pragma unroll
    for (int j = 0; j < 4; j++) {
        float ss = 0.f;
#pragma unroll
        for (int nf = 0; nf < 8; nf++) ss += acc[nf][j] * acc[nf][j];
        ss += __shfl_xor(ss, 1, 64); ss += __shfl_xor(ss, 2, 64);
        ss += __shfl_xor(ss, 4, 64); ss += __shfl_xor(ss, 8, 64);
        inv[j] = 1.0f / fmaxf(sqrtf(ss), 1e-12f);
    }
#pragma unroll
    for (int nf = 0; nf < 8; nf++) {
        int col = nf * 16 + l15;
        float s = 0.f, q = 0.f;
#pragma unroll
        for (int j = 0; j < 4; j++) {
            int row = rb + w * 16 + grp * 4 + j;
            float u = acc[nf][j] * inv[j];
            if (row < n) {
                out[(size_t)row * H + col] = f2bf(u);
                s += u; q += u * u;
            }
        }
        s += __shfl_xor(s, 16, 64); s += __shfl_xor(s, 32, 64);
        q += __shfl_xor(q, 16, 64); q += __shfl_xor(q, 32, 64);
        if (grp == 0) { atomicAdd(&cs[col], s); atomicAdd(&css[col], q); }
    }
    __syncthreads();
    if (tid < 128) { atomicAdd(gsum + tid, cs[tid]); atomicAdd(gsumsq + tid, css[tid]); }
}

__global__ __launch_bounds__(512) void k_gemm_sage(
    const u16* __restrict__ Am, const u16* __restrict__ Ab,
    const u16* __restrict__ WlT, const u16* __restrict__ WrT,
    const float* __restrict__ bl, u16* __restrict__ out,
    float* __restrict__ gsum, float* __restrict__ gsumsq, int n)
{
    __shared__ u16 sA[128 * 128];
    __shared__ u16 sB[128 * 128];
    __shared__ float cs[128], css[128];
    const int tid = threadIdx.x;
    const int rb = blockIdx.x * 128;
    if (tid < 128) { cs[tid] = 0.f; css[tid] = 0.f; }
    const int w = tid >> 6, l15 = tid & 15, grp = (tid & 63) >> 4;
    f4 acc[8] = {};

#pragma unroll
    for (int j = 0; j < 4; j++) {
        int f = j * 512 + tid;
        int r = f >> 4, g = f & 15;
        int row = rb + r;
        uint4 v = {0, 0, 0, 0};
        if (row < n) v = *reinterpret_cast<const uint4*>(Am + (size_t)row * H + g * 8);
        *reinterpret_cast<uint4*>((char*)sA + swz(r, g * 16)) = v;
    }
#pragma unroll
    for (int j = 0; j < 4; j++) {
        int f = j * 512 + tid;
        int r = f >> 4, kb = f & 15;
        uint4 v = *reinterpret_cast<const uint4*>(WlT + r * H + kb * 8);
        *reinterpret_cast<uint4*>((char*)sB + swz(r, kb * 16)) = v;
    }
    __syncthreads();
#pragma unroll
    for (int kc = 0; kc < 4; kc++) {
        bh8 af = *reinterpret_cast<const bh8*>((char*)sA + swz(w * 16 + l15, kc * 64 + grp * 16));
#pragma unroll
        for (int nf = 0; nf < 8; nf++) {
            bh8 bv = *reinterpret_cast<const bh8*>((char*)sB + swz(nf * 16 + l15, kc * 64 + grp * 16));
            acc[nf] = __builtin_amdgcn_mfma_f32_16x16x32_bf16(af, bv, acc[nf], 0, 0, 0);
        }
    }
    __syncthreads();

#pragma unroll
    for (int j = 0; j < 4; j++) {
        int f = j * 512 + tid;
        int r = f >> 4, g = f & 15;
        int row = rb + r;
        uint4 v = {0, 0, 0, 0};
        if (row < n) v = *reinterpret_cast<const uint4*>(Ab + (size_t)row * H + g * 8);
        *reinterpret_cast<uint4*>((char*)sA + swz(r, g * 16)) = v;
    }
#pragma unroll
    for (int j = 0; j < 4; j++) {
        int f = j * 512 + tid;
        int r = f >> 4, kb = f & 15;
        uint4 v = *reinterpret_cast<const uint4*>(WrT + r * H + kb * 8);
        *reinterpret_cast<uint4*>((char*)sB + swz(r, kb * 16)) = v;
    }
    __syncthreads();
#pragma unroll
    for (int kc = 0; kc < 4; kc++) {
        bh8 af = *reinterpret_cast<const bh8*>((char*)sA + swz(w * 16 + l15, kc * 64 + grp * 16));
#pragma unroll
        for (int nf = 0; nf < 8; nf++) {
            bh8 bv = *reinterpret_cast<const bh8*>((char*)sB + swz(nf * 16 + l15, kc * 64 + grp * 16));
            acc[nf] = __builtin_amdgcn_mfma_f32_16x16x32_bf16(af, bv, acc[nf], 0, 0, 0);
        }
    }

#pragma unroll
    for (int nf = 0; nf < 8; nf++) {
        int col = nf * 16 + l15;
        float bc = bl[col];
        float s = 0.f, q = 0.f;
#pragma unroll
        for (int j = 0; j < 4; j++) {
            int row = rb + w * 16 + grp * 4 + j;
            float u = acc[nf][j] + bc;
            if (row < n) {
                out[(size_t)row * H + col] = f2bf(u);
                s += u; q += u * u;
            }
        }
        s += __shfl_xor(s, 16, 64); s += __shfl_xor(s, 32, 64);
        q += __shfl_xor(q, 16, 64); q += __shfl_xor(q, 32, 64);
        if (grp == 0) { atomicAdd(&cs[col], s); atomicAdd(&css[col], q); }
    }
    __syncthreads();
    if (tid < 128) { atomicAdd(gsum + tid, cs[tid]); atomicAdd(gsumsq + tid, css[tid]); }
}

__global__ void k_bnparams(const float* __restrict__ gsum, const float* __restrict__ gsumsq,
                           const float* __restrict__ g, const float* __restrict__ b,
                           float* __restrict__ scale, float* __restrict__ shift, float inv_n)
{
    int c = threadIdx.x;
    float mu = gsum[c] * inv_n;
    float var = fmaxf(gsumsq[c] * inv_n - mu * mu, 0.f);
    float sc = g[c] * rsqrtf(var + BN_EPS);
    scale[c] = sc;
    shift[c] = b[c] - mu * sc;
}

// GCN dense: write split xlo/xhi (dinv-prescaled bf16)
__global__ __launch_bounds__(320) void k_gcn(
    const u16* __restrict__ H2, const float* __restrict__ scale2, const float* __restrict__ shift2,
    const float* __restrict__ Wg, const float* __restrict__ dinv,
    u16* __restrict__ xlo, u16* __restrict__ xhi, int n)
{
    __shared__ float sW[H * OUTD];
    __shared__ float sA[32][H];
    const int tid = threadIdx.x;
#pragma unroll
    for (int j = 0; j < 4; j++) {
        int off = (tid + j * 320) * 4;
        *reinterpret_cast<float4*>(&sW[off]) = ld4(Wg + off);
    }
    const int rb = blockIdx.x * 32;
#pragma unroll
    for (int j = 0; j < 2; j++) {
        int li = tid + j * 320;
        if (li < 512) {
            int r = li >> 4, g = li & 15;
            int row = rb + r;
            float4 v0 = {0.f, 0.f, 0.f, 0.f}, v1 = {0.f, 0.f, 0.f, 0.f};
            if (row < n) {
                uint4 a = *reinterpret_cast<const uint4*>(H2 + (size_t)row * H + g * 8);
                float4 sc0 = ld4(scale2 + g * 8), sc1 = ld4(scale2 + g * 8 + 4);
                float4 sh0 = ld4(shift2 + g * 8), sh1 = ld4(shift2 + g * 8 + 4);
                v0.x = fmaxf(bflo(a.x) * sc0.x + sh0.x, 0.f);
                v0.y = fmaxf(bfhi(a.x) * sc0.y + sh0.y, 0.f);
                v0.z = fmaxf(bflo(a.y) * sc0.z + sh0.z, 0.f);
                v0.w = fmaxf(bfhi(a.y) * sc0.w + sh0.w, 0.f);
                v1.x = fmaxf(bflo(a.z) * sc1.x + sh1.x, 0.f);
                v1.y = fmaxf(bfhi(a.z) * sc1.y + sh1.y, 0.f);
                v1.z = fmaxf(bflo(a.w) * sc1.z + sh1.z, 0.f);
                v1.w = fmaxf(bfhi(a.w) * sc1.w + sh1.w, 0.f);
            }
            *reinterpret_cast<float4*>(&sA[r][g * 8]) = v0;
            *reinterpret_cast<float4*>(&sA[r][g * 8 + 4]) = v1;
        }
    }
    __syncthreads();
    const int c = tid % OUTD;
    const int rg = tid / OUTD;
    float acc[4] = {0.f, 0.f, 0.f, 0.f};
    for (int k = 0; k < H; k++) {
        float w = sW[k * OUTD + c];
#pragma unroll
        for (int i = 0; i < 4; i++) acc[i] += sA[rg + i * 8][k] * w;
    }
#pragma unroll
    for (int i = 0; i < 4; i++) {
        int row = rb + rg + i * 8;
        if (row < n) {
            u16 v = f2bf(dinv[row] * acc[i]);
            if (c < 32) xlo[(size_t)row * 32 + c] = v;
            else        xhi[(size_t)row * 8 + (c - 32)] = v;
        }
    }
}

extern "C" void kernel_launch(void* const* d_in, const int* in_sizes, int n_in,
                              void* d_out, int out_size, void* d_ws, size_t ws_size,
                              hipStream_t stream)
{
    const float* x     = (const float*)d_in[0];
    const int*   ei    = (const int*)d_in[1];
    const float* w1    = (const float*)d_in[2];
    const float* b1    = (const float*)d_in[3];
    const float* w2    = (const float*)d_in[4];
    const float* b2    = (const float*)d_in[5];
    const float* bn1g  = (const float*)d_in[6];
    const float* bn1b  = (const float*)d_in[7];
    const float* wl    = (const float*)d_in[8];
    const float* bls   = (const float*)d_in[9];
    const float* wr    = (const float*)d_in[10];
    const float* bn2g  = (const float*)d_in[11];
    const float* bn2b  = (const float*)d_in[12];
    const float* wg    = (const float*)d_in[13];
    const float* bg    = (const float*)d_in[14];

    const int N = in_sizes[0] / H;
    const int E = in_sizes[1] / 2;
    const int* src = ei;
    const int* dst = ei + E;
    float* outp = (float*)d_out;

    const int NRANGE = (N + RSIZE - 1) >> RBITS;

    u16* P0   = (u16*)d_ws;
    u16* P1   = P0 + (size_t)N * H;
    u16* P2   = P1 + (size_t)N * H;
    u16* xlo  = P2 + (size_t)N * H;              // N*32 bf16 (64B rows)
    u16* xhi  = xlo + (size_t)N * 32;            // N*8 bf16 (1.6MB, L2-resident)
    float* dinv = (float*)(xhi + (size_t)N * 8);
    float* st   = dinv + N;
    int*  deg   = (int*)(st + 1024);
    int*  cursor= deg + N;
    int*  bsum  = cursor + N;
    int*  csr   = bsum + 1024;
    u16* wt1 = (u16*)(csr + E);
    u16* wt2 = wt1 + 16384;
    u16* wtl = wt2 + 16384;
    u16* wtr = wtl + 16384;
    u32* partial = (u32*)P0;
    float* sum1 = st,        *sumsq1 = st + 128;
    float* sum2 = st + 256,  *sumsq2 = st + 384;
    float* scale1 = st + 512, *shift1 = st + 640;
    float* scale2 = st + 768, *shift2 = st + 896;

    hipMemsetAsync(st, 0, 1024 * sizeof(float), stream);

    const int nb = (N + 1023) / 1024;
    const int total8 = N * H / 8;
    const int csrblk = NXCD * NB;

    k_prep<<<256, 256, 0, stream>>>(w1, w2, wl, wr, wt1, wt2, wtl, wtr);
    k_hist2<<<csrblk, 256, 0, stream>>>(dst, partial, E, NRANGE);
    k_scan1<<<nb, 256, 0, stream>>>(partial, deg, cursor, bsum, N);
    k_scan2<<<1, 256, 0, stream>>>(bsum, nb);
    k_scan3<<<(N + 255) / 256, 256, 0, stream>>>(cursor, bsum, deg, dinv, N);
    k_fill2<<<csrblk, 256, 0, stream>>>(src, dst, cursor, partial, csr, E, NRANGE);

    k_xbf<<<(total8 + 255) / 256, 256, 0, stream>>>(x, P2, total8);

    const int aggblk4 = (N + 15) / 16;
    const int gblocks = (N + 127) / 128;

    // ---- layer 1 ----
    k_agg1<<<aggblk4, 256, 0, stream>>>(P2, csr, cursor, deg, P0, N);
    k_gemm_film<<<gblocks, 512, 0, stream>>>(P0, wt1, b1, wt2, b2, P2, sum1, sumsq1, N);
    k_bnparams<<<1, 128, 0, stream>>>(sum1, sumsq1, bn1g, bn1b, scale1, shift1, 1.0f / N);

    // ---- layer 2 ----
    k_act1<<<(total8 + 255) / 256, 256, 0, stream>>>(P2, scale1, shift1, P0, total8);
    k_agg2<<<aggblk4, 256, 0, stream>>>(P0, csr, cursor, deg, P1, N);
    k_gemm_sage<<<gblocks, 512, 0, stream>>>(P1, P0, wtl, wtr, bls, P1, sum2, sumsq2, N);
    k_bnparams<<<1, 128, 0, stream>>>(sum2, sumsq2, bn2g, bn2b, scale2, shift2, 1.0f / N);

    // ---- layer 3 ----
    k_gcn<<<(N + 31) / 32, 320, 0, stream>>>(P1, scale2, shift2, wg, dinv, xlo, xhi, N);
    k_agg3<<<(N * 64 + 255) / 256, 256, 0, stream>>>(xlo, xhi, dinv, csr, cursor, deg, bg, outp, N);
}

// Round 16
// 414.388 us; speedup vs baseline: 1.0504x; 1.0504x over previous
//
#include <hip/hip_runtime.h>
#include <math.h>

#define H 128
#define OUTD 40
#define BN_EPS 1e-5f
#define NEG_SLOPE 0.01f
#define RBITS 14
#define RSIZE 16384
#define NB 128           // edge chunks per range
#define NXCD 8

typedef __attribute__((ext_vector_type(8))) short bh8;
typedef __attribute__((ext_vector_type(4))) float f4;
typedef unsigned short u16;
typedef unsigned int u32;

__device__ __forceinline__ float4 ld4(const float* p) {
    return *reinterpret_cast<const float4*>(p);
}
__device__ __forceinline__ u16 f2bf(float f) {
    unsigned int u = __float_as_uint(f);
    u += 0x7fffu + ((u >> 16) & 1u);          // RNE
    return (u16)(u >> 16);
}
__device__ __forceinline__ float bflo(unsigned d) { return __uint_as_float(d << 16); }
__device__ __forceinline__ float bfhi(unsigned d) { return __uint_as_float(d & 0xffff0000u); }
__device__ __forceinline__ unsigned pk(float a, float b) {
    return (unsigned)f2bf(a) | ((unsigned)f2bf(b) << 16);
}
__device__ __forceinline__ int swz(int row, int byteInRow) {
    return row * 256 + (byteInRow ^ ((row & 7) << 4));
}

// ================= x -> bf16 =================
__global__ __launch_bounds__(256) void k_xbf(
    const float* __restrict__ x, u16* __restrict__ xb, int total8)
{
    int i = blockIdx.x * 256 + threadIdx.x;
    if (i >= total8) return;
    float4 a = ld4(x + (size_t)i * 8);
    float4 b = ld4(x + (size_t)i * 8 + 4);
    uint4 o;
    o.x = pk(a.x, a.y); o.y = pk(a.z, a.w);
    o.z = pk(b.x, b.y); o.w = pk(b.z, b.w);
    *reinterpret_cast<uint4*>(xb + (size_t)i * 8) = o;
}

// ================= weight prep: WT[c][k] = bf16(W[k][c]) =================
__global__ __launch_bounds__(256) void k_prep(
    const float* __restrict__ w1, const float* __restrict__ w2,
    const float* __restrict__ wl, const float* __restrict__ wr,
    u16* __restrict__ wt1, u16* __restrict__ wt2,
    u16* __restrict__ wtl, u16* __restrict__ wtr)
{
    int id = blockIdx.x * 256 + threadIdx.x;
    int sel = id >> 14;
    int o = id & 16383;
    int c = o >> 7, k = o & 127;
    const float* w = (sel == 0) ? w1 : (sel == 1) ? w2 : (sel == 2) ? wl : wr;
    u16* wt = (sel == 0) ? wt1 : (sel == 1) ? wt2 : (sel == 2) ? wtl : wtr;
    wt[o] = f2bf(w[k * H + c]);
}

// ================= CSR build (atomic-free, XCD-pinned) =================
__global__ __launch_bounds__(256) void k_hist2(
    const int* __restrict__ dst, u32* __restrict__ partial, int E, int nrange)
{
    __shared__ u32 hcnt[RSIZE / 2];
    const int tid = threadIdx.x;
    const int r = blockIdx.x & (NXCD - 1), bb = blockIdx.x >> 3;
    if (r >= nrange) return;
    for (int t = tid; t < RSIZE / 2; t += 256) hcnt[t] = 0;
    __syncthreads();
    const int lo = r << RBITS;
    const int chunk = (E + NB - 1) / NB;
    const int s0 = bb * chunk;
    const int s1 = min(E, s0 + chunk);
    for (int e = s0 + tid; e < s1; e += 256) {
        unsigned local = (unsigned)(dst[e] - lo);
        if (local < (unsigned)RSIZE)
            atomicAdd(&hcnt[local >> 1], 1u << ((local & 1) << 4));
    }
    __syncthreads();
    u32* out = partial + ((size_t)(r * NB + bb) << 13);
    for (int t = tid; t < RSIZE / 2; t += 256) out[t] = hcnt[t];
}

__global__ __launch_bounds__(256) void k_scan1(
    u32* __restrict__ partial, int* __restrict__ deg,
    int* __restrict__ cursor, int* __restrict__ bsum, int n)
{
    __shared__ int sums[256];
    const int tid = threadIdx.x;
    const int idx = blockIdx.x * 1024 + tid * 4;
    const int r = idx >> RBITS;
    const int jw = (idx & (RSIZE - 1)) >> 1;
    uint2 acc = {0u, 0u};
    for (int bb = 0; bb < NB; bb++) {
        u32* p = partial + (((size_t)(r * NB + bb)) << 13) + jw;
        uint2 w = *reinterpret_cast<uint2*>(p);
        *reinterpret_cast<uint2*>(p) = acc;
        acc.x += w.x; acc.y += w.y;
    }
    int4 v;
    v.x = (int)(acc.x & 0xFFFFu); v.y = (int)(acc.x >> 16);
    v.z = (int)(acc.y & 0xFFFFu); v.w = (int)(acc.y >> 16);
    if (idx + 0 >= n) v.x = 0;
    if (idx + 1 >= n) v.y = 0;
    if (idx + 2 >= n) v.z = 0;
    if (idx + 3 >= n) v.w = 0;
    if (idx + 3 < n) *reinterpret_cast<int4*>(deg + idx) = v;
    else {
        if (idx + 0 < n) deg[idx + 0] = v.x;
        if (idx + 1 < n) deg[idx + 1] = v.y;
        if (idx + 2 < n) deg[idx + 2] = v.z;
        if (idx + 3 < n) deg[idx + 3] = v.w;
    }
    int t = v.x + v.y + v.z + v.w;
    sums[tid] = t;
    __syncthreads();
    for (int off = 1; off < 256; off <<= 1) {
        int other = (tid >= off) ? sums[tid - off] : 0;
        __syncthreads();
        sums[tid] += other;
        __syncthreads();
    }
    int incl = sums[tid];
    int excl = incl - t;
    if (tid == 255) bsum[blockIdx.x] = incl;
    int c0 = excl, c1 = c0 + v.x, c2 = c1 + v.y, c3 = c2 + v.z;
    if (idx + 3 < n) {
        int4 o = {c0, c1, c2, c3};
        *reinterpret_cast<int4*>(cursor + idx) = o;
    } else {
        if (idx + 0 < n) cursor[idx + 0] = c0;
        if (idx + 1 < n) cursor[idx + 1] = c1;
        if (idx + 2 < n) cursor[idx + 2] = c2;
        if (idx + 3 < n) cursor[idx + 3] = c3;
    }
}

__global__ void k_scan2(int* __restrict__ bsum, int nb)
{
    __shared__ int s[1024];
    const int tid = threadIdx.x;
    for (int i = tid; i < nb; i += blockDim.x) s[i] = bsum[i];
    __syncthreads();
    if (tid == 0) {
        int acc = 0;
        for (int i = 0; i < nb; i++) { int t = s[i]; s[i] = acc; acc += t; }
    }
    __syncthreads();
    for (int i = tid; i < nb; i += blockDim.x) bsum[i] = s[i];
}

__global__ __launch_bounds__(256) void k_scan3(
    int* __restrict__ cursor, const int* __restrict__ bsum,
    const int* __restrict__ deg, float* __restrict__ dinv, int n)
{
    int i = blockIdx.x * 256 + threadIdx.x;
    if (i < n) {
        cursor[i] += bsum[i >> 10];
        dinv[i] = rsqrtf((float)deg[i] + 1.0f);
    }
}

__global__ __launch_bounds__(256) void k_fill2(
    const int* __restrict__ src, const int* __restrict__ dst,
    const int* __restrict__ cursor, const u32* __restrict__ partial,
    int* __restrict__ csr, int E, int nrange)
{
    __shared__ u32 rcnt[RSIZE / 2];
    const int tid = threadIdx.x;
    const int r = blockIdx.x & (NXCD - 1), bb = blockIdx.x >> 3;
    if (r >= nrange) return;
    for (int t = tid; t < RSIZE / 2; t += 256) rcnt[t] = 0;
    __syncthreads();
    const int lo = r << RBITS;
    const int chunk = (E + NB - 1) / NB;
    const int s0 = bb * chunk;
    const int s1 = min(E, s0 + chunk);
    const u32* pref = partial + ((size_t)(r * NB + bb) << 13);
    for (int e = s0 + tid; e < s1; e += 256) {
        int d = dst[e];
        unsigned local = (unsigned)(d - lo);
        if (local < (unsigned)RSIZE) {
            unsigned sh = (local & 1) << 4;
            unsigned old = atomicAdd(&rcnt[local >> 1], 1u << sh);
            unsigned rank = (old >> sh) & 0xFFFFu;
            unsigned pfx = (pref[local >> 1] >> sh) & 0xFFFFu;
            csr[cursor[d] + (int)pfx + (int)rank] = src[e];
        }
    }
}

// ================= gather aggregations (bf16 features) =================
__global__ __launch_bounds__(256) void k_agg1(
    const u16* __restrict__ xb, const int* __restrict__ csr,
    const int* __restrict__ cursor, const int* __restrict__ deg,
    u16* __restrict__ out, int n)
{
    int wave = (blockIdx.x * 256 + threadIdx.x) >> 6;
    int lane = threadIdx.x & 63;
    int row = wave * 4 + (lane >> 4);
    if (row >= n) return;
    int g = lane & 15;
    int start = cursor[row];
    int end = start + deg[row];
    float acc[8] = {0.f, 0.f, 0.f, 0.f, 0.f, 0.f, 0.f, 0.f};
    int i = start;
    for (; i + 4 <= end; i += 4) {
        int s0 = csr[i], s1 = csr[i + 1], s2 = csr[i + 2], s3 = csr[i + 3];
        uint4 a = *reinterpret_cast<const uint4*>(xb + (size_t)s0 * H + g * 8);
        uint4 b = *reinterpret_cast<const uint4*>(xb + (size_t)s1 * H + g * 8);
        uint4 c = *reinterpret_cast<const uint4*>(xb + (size_t)s2 * H + g * 8);
        uint4 d = *reinterpret_cast<const uint4*>(xb + (size_t)s3 * H + g * 8);
        acc[0] += (bflo(a.x) + bflo(b.x)) + (bflo(c.x) + bflo(d.x));
        acc[1] += (bfhi(a.x) + bfhi(b.x)) + (bfhi(c.x) + bfhi(d.x));
        acc[2] += (bflo(a.y) + bflo(b.y)) + (bflo(c.y) + bflo(d.y));
        acc[3] += (bfhi(a.y) + bfhi(b.y)) + (bfhi(c.y) + bfhi(d.y));
        acc[4] += (bflo(a.z) + bflo(b.z)) + (bflo(c.z) + bflo(d.z));
        acc[5] += (bfhi(a.z) + bfhi(b.z)) + (bfhi(c.z) + bfhi(d.z));
        acc[6] += (bflo(a.w) + bflo(b.w)) + (bflo(c.w) + bflo(d.w));
        acc[7] += (bfhi(a.w) + bfhi(b.w)) + (bfhi(c.w) + bfhi(d.w));
    }
    for (; i < end; i++) {
        int s = csr[i];
        uint4 a = *reinterpret_cast<const uint4*>(xb + (size_t)s * H + g * 8);
        acc[0] += bflo(a.x); acc[1] += bfhi(a.x);
        acc[2] += bflo(a.y); acc[3] += bfhi(a.y);
        acc[4] += bflo(a.z); acc[5] += bfhi(a.z);
        acc[6] += bflo(a.w); acc[7] += bfhi(a.w);
    }
    uint4 o;
    o.x = pk(acc[0], acc[1]); o.y = pk(acc[2], acc[3]);
    o.z = pk(acc[4], acc[5]); o.w = pk(acc[6], acc[7]);
    *reinterpret_cast<uint4*>(out + (size_t)row * H + g * 8) = o;
}

// act1h = bf16(relu(affine1(h))), elementwise
__global__ __launch_bounds__(256) void k_act1(
    const u16* __restrict__ hb, const float* __restrict__ scale, const float* __restrict__ shift,
    u16* __restrict__ out, int total8)
{
    int i = blockIdx.x * 256 + threadIdx.x;
    if (i >= total8) return;
    int g = i & 15;
    uint4 a = *reinterpret_cast<const uint4*>(hb + (size_t)i * 8);
    float4 sc0 = ld4(scale + g * 8), sc1 = ld4(scale + g * 8 + 4);
    float4 sh0 = ld4(shift + g * 8), sh1 = ld4(shift + g * 8 + 4);
    float e0 = fmaxf(bflo(a.x) * sc0.x + sh0.x, 0.f);
    float e1 = fmaxf(bfhi(a.x) * sc0.y + sh0.y, 0.f);
    float e2 = fmaxf(bflo(a.y) * sc0.z + sh0.z, 0.f);
    float e3 = fmaxf(bfhi(a.y) * sc0.w + sh0.w, 0.f);
    float e4 = fmaxf(bflo(a.z) * sc1.x + sh1.x, 0.f);
    float e5 = fmaxf(bfhi(a.z) * sc1.y + sh1.y, 0.f);
    float e6 = fmaxf(bflo(a.w) * sc1.z + sh1.z, 0.f);
    float e7 = fmaxf(bfhi(a.w) * sc1.w + sh1.w, 0.f);
    uint4 o;
    o.x = pk(e0, e1); o.y = pk(e2, e3); o.z = pk(e4, e5); o.w = pk(e6, e7);
    *reinterpret_cast<uint4*>(out + (size_t)i * 8) = o;
}

__global__ __launch_bounds__(256) void k_agg2(
    const u16* __restrict__ ab, const int* __restrict__ csr,
    const int* __restrict__ cursor, const int* __restrict__ deg,
    u16* __restrict__ out, int n)
{
    int wave = (blockIdx.x * 256 + threadIdx.x) >> 6;
    int lane = threadIdx.x & 63;
    int row = wave * 4 + (lane >> 4);
    if (row >= n) return;
    int g = lane & 15;
    int dg = deg[row];
    int start = cursor[row];
    int end = start + dg;
    float acc[8] = {0.f, 0.f, 0.f, 0.f, 0.f, 0.f, 0.f, 0.f};
    int i = start;
    for (; i + 4 <= end; i += 4) {
        int s0 = csr[i], s1 = csr[i + 1], s2 = csr[i + 2], s3 = csr[i + 3];
        uint4 a = *reinterpret_cast<const uint4*>(ab + (size_t)s0 * H + g * 8);
        uint4 b = *reinterpret_cast<const uint4*>(ab + (size_t)s1 * H + g * 8);
        uint4 c = *reinterpret_cast<const uint4*>(ab + (size_t)s2 * H + g * 8);
        uint4 d = *reinterpret_cast<const uint4*>(ab + (size_t)s3 * H + g * 8);
        acc[0] += (bflo(a.x) + bflo(b.x)) + (bflo(c.x) + bflo(d.x));
        acc[1] += (bfhi(a.x) + bfhi(b.x)) + (bfhi(c.x) + bfhi(d.x));
        acc[2] += (bflo(a.y) + bflo(b.y)) + (bflo(c.y) + bflo(d.y));
        acc[3] += (bfhi(a.y) + bfhi(b.y)) + (bfhi(c.y) + bfhi(d.y));
        acc[4] += (bflo(a.z) + bflo(b.z)) + (bflo(c.z) + bflo(d.z));
        acc[5] += (bfhi(a.z) + bfhi(b.z)) + (bfhi(c.z) + bfhi(d.z));
        acc[6] += (bflo(a.w) + bflo(b.w)) + (bflo(c.w) + bflo(d.w));
        acc[7] += (bfhi(a.w) + bfhi(b.w)) + (bfhi(c.w) + bfhi(d.w));
    }
    for (; i < end; i++) {
        int s = csr[i];
        uint4 a = *reinterpret_cast<const uint4*>(ab + (size_t)s * H + g * 8);
        acc[0] += bflo(a.x); acc[1] += bfhi(a.x);
        acc[2] += bflo(a.y); acc[3] += bfhi(a.y);
        acc[4] += bflo(a.z); acc[5] += bfhi(a.z);
        acc[6] += bflo(a.w); acc[7] += bfhi(a.w);
    }
    float idv = 1.0f / fmaxf((float)dg, 1.0f);
    uint4 o;
    o.x = pk(acc[0] * idv, acc[1] * idv); o.y = pk(acc[2] * idv, acc[3] * idv);
    o.z = pk(acc[4] * idv, acc[5] * idv); o.w = pk(acc[6] * idv, acc[7] * idv);
    *reinterpret_cast<uint4*>(out + (size_t)row * H + g * 8) = o;
}

// GCN gather + self-loop + bias + log-softmax.
// xwsp[N][64] bf16 (128B rows, cols 40..63 pad). Wave = 4 rows x 16 lanes;
// lane g holds cols g*4..g*4+3 (uint2 per neighbor). Lanes g>=10 masked.
__global__ __launch_bounds__(256) void k_agg3(
    const u16* __restrict__ xwsp, const float* __restrict__ dinv,
    const int* __restrict__ csr, const int* __restrict__ cursor, const int* __restrict__ deg,
    const float* __restrict__ bias, float* __restrict__ outp, int n)
{
    int wave = (blockIdx.x * 256 + threadIdx.x) >> 6;
    int lane = threadIdx.x & 63;
    int row = wave * 4 + (lane >> 4);
    if (row >= n) return;
    int g = lane & 15;
    bool act = g < 10;
    const u16* base = xwsp + g * 4;
    int start = cursor[row];
    int end = start + deg[row];
    float a0 = 0.f, a1 = 0.f, a2 = 0.f, a3 = 0.f;
    int i = start;
    for (; i + 4 <= end; i += 4) {
        int s0 = csr[i], s1 = csr[i + 1], s2 = csr[i + 2], s3 = csr[i + 3];
        uint2 u0 = *reinterpret_cast<const uint2*>(base + (size_t)s0 * 64);
        uint2 u1 = *reinterpret_cast<const uint2*>(base + (size_t)s1 * 64);
        uint2 u2 = *reinterpret_cast<const uint2*>(base + (size_t)s2 * 64);
        uint2 u3 = *reinterpret_cast<const uint2*>(base + (size_t)s3 * 64);
        a0 += (bflo(u0.x) + bflo(u1.x)) + (bflo(u2.x) + bflo(u3.x));
        a1 += (bfhi(u0.x) + bfhi(u1.x)) + (bfhi(u2.x) + bfhi(u3.x));
        a2 += (bflo(u0.y) + bflo(u1.y)) + (bflo(u2.y) + bflo(u3.y));
        a3 += (bfhi(u0.y) + bfhi(u1.y)) + (bfhi(u2.y) + bfhi(u3.y));
    }
    for (; i < end; i++) {
        uint2 u = *reinterpret_cast<const uint2*>(base + (size_t)csr[i] * 64);
        a0 += bflo(u.x); a1 += bfhi(u.x);
        a2 += bflo(u.y); a3 += bfhi(u.y);
    }
    uint2 sf = *reinterpret_cast<const uint2*>(base + (size_t)row * 64);
    float di = dinv[row];
    float4 bb = {0.f, 0.f, 0.f, 0.f};
    if (act) bb = ld4(bias + g * 4);
    float v0 = di * (a0 + bflo(sf.x)) + bb.x;
    float v1 = di * (a1 + bfhi(sf.x)) + bb.y;
    float v2 = di * (a2 + bflo(sf.y)) + bb.z;
    float v3 = di * (a3 + bfhi(sf.y)) + bb.w;
    float m = act ? fmaxf(fmaxf(v0, v1), fmaxf(v2, v3)) : -INFINITY;
#pragma unroll
    for (int s = 1; s < 16; s <<= 1) m = fmaxf(m, __shfl_xor(m, s, 64));
    float e0 = act ? expf(v0 - m) : 0.f;
    float e1 = act ? expf(v1 - m) : 0.f;
    float e2 = act ? expf(v2 - m) : 0.f;
    float e3 = act ? expf(v3 - m) : 0.f;
    float sum = (e0 + e1) + (e2 + e3);
#pragma unroll
    for (int s = 1; s < 16; s <<= 1) sum += __shfl_xor(sum, s, 64);
    float l = logf(sum) + m;
    if (act) {
        float4 o = {v0 - l, v1 - l, v2 - l, v3 - l};
        *reinterpret_cast<float4*>(outp + (size_t)row * OUTD + g * 4) = o;
    }
}

// ================= MFMA dense layers (128-row tiles, 512 threads) =================
__global__ __launch_bounds__(512) void k_gemm_film(
    const u16* __restrict__ A, const u16* __restrict__ W1T, const float* __restrict__ b1,
    const u16* __restrict__ W2T, const float* __restrict__ b2,
    u16* __restrict__ out, float* __restrict__ gsum, float* __restrict__ gsumsq, int n)
{
    __shared__ u16 sA[128 * 128];
    __shared__ u16 sB[128 * 128];
    __shared__ float cs[128], css[128];
    const int tid = threadIdx.x;
    const int rb = blockIdx.x * 128;
    if (tid < 128) { cs[tid] = 0.f; css[tid] = 0.f; }
    const int w = tid >> 6, l15 = tid & 15, grp = (tid & 63) >> 4;

#pragma unroll
    for (int j = 0; j < 4; j++) {
        int f = j * 512 + tid;
        int r = f >> 4, g = f & 15;
        int row = rb + r;
        uint4 v = {0, 0, 0, 0};
        if (row < n) v = *reinterpret_cast<const uint4*>(A + (size_t)row * H + g * 8);
        *reinterpret_cast<uint4*>((char*)sA + swz(r, g * 16)) = v;
    }
#pragma unroll
    for (int j = 0; j < 4; j++) {
        int f = j * 512 + tid;
        int r = f >> 4, kb = f & 15;
        uint4 v = *reinterpret_cast<const uint4*>(W1T + r * H + kb * 8);
        *reinterpret_cast<uint4*>((char*)sB + swz(r, kb * 16)) = v;
    }
    __syncthreads();
    f4 acc[8] = {};
#pragma unroll
    for (int kc = 0; kc < 4; kc++) {
        bh8 af = *reinterpret_cast<const bh8*>((char*)sA + swz(w * 16 + l15, kc * 64 + grp * 16));
#pragma unroll
        for (int nf = 0; nf < 8; nf++) {
            bh8 bv = *reinterpret_cast<const bh8*>((char*)sB + swz(nf * 16 + l15, kc * 64 + grp * 16));
            acc[nf] = __builtin_amdgcn_mfma_f32_16x16x32_bf16(af, bv, acc[nf], 0, 0, 0);
        }
    }
    __syncthreads();

#pragma unroll
    for (int nf = 0; nf < 8; nf++) {
        int col = nf * 16 + l15;
        float bc = b1[col];
#pragma unroll
        for (int j = 0; j < 4; j++) {
            int row = w * 16 + grp * 4 + j;
            float u = acc[nf][j] + bc;
            u = u > 0.f ? u : NEG_SLOPE * u;
            *reinterpret_cast<u16*>((char*)sA + swz(row, col * 2)) = f2bf(u);
        }
        acc[nf] = f4{0.f, 0.f, 0.f, 0.f};
    }
#pragma unroll
    for (int j = 0; j < 4; j++) {
        int f = j * 512 + tid;
        int r = f >> 4, kb = f & 15;
        uint4 v = *reinterpret_cast<const uint4*>(W2T + r * H + kb * 8);
        *reinterpret_cast<uint4*>((char*)sB + swz(r, kb * 16)) = v;
    }
    __syncthreads();

#pragma unroll
    for (int kc = 0; kc < 4; kc++) {
        bh8 af = *reinterpret_cast<const bh8*>((char*)sA + swz(w * 16 + l15, kc * 64 + grp * 16));
#pragma unroll
        for (int nf = 0; nf < 8; nf++) {
            bh8 bv = *reinterpret_cast<const bh8*>((char*)sB + swz(nf * 16 + l15, kc * 64 + grp * 16));
            acc[nf] = __builtin_amdgcn_mfma_f32_16x16x32_bf16(af, bv, acc[nf], 0, 0, 0);
        }
    }

#pragma unroll
    for (int nf = 0; nf < 8; nf++) {
        float bc = b2[nf * 16 + l15];
#pragma unroll
        for (int j = 0; j < 4; j++) acc[nf][j] += bc;
    }
    float inv[4];
#pragma unroll
    for (int j = 0; j < 4; j++) {
        float ss = 0.f;
#pragma unroll
        for (int nf = 0; nf < 8; nf++) ss += acc[nf][j] * acc[nf][j];
        ss += __shfl_xor(ss, 1, 64); ss += __shfl_xor(ss, 2, 64);
        ss += __shfl_xor(ss, 4, 64); ss += __shfl_xor(ss, 8, 64);
        inv[j] = 1.0f / fmaxf(sqrtf(ss), 1e-12f);
    }
#pragma unroll
    for (int nf = 0; nf < 8; nf++) {
        int col = nf * 16 + l15;
        float s = 0.f, q = 0.f;
#pragma unroll
        for (int j = 0; j < 4; j++) {
            int row = rb + w * 16 + grp * 4 + j;
            float u = acc[nf][j] * inv[j];
            if (row < n) {
                out[(size_t)row * H + col] = f2bf(u);
                s += u; q += u * u;
            }
        }
        s += __shfl_xor(s, 16, 64); s += __shfl_xor(s, 32, 64);
        q += __shfl_xor(q, 16, 64); q += __shfl_xor(q, 32, 64);
        if (grp == 0) { atomicAdd(&cs[col], s); atomicAdd(&css[col], q); }
    }
    __syncthreads();
    if (tid < 128) { atomicAdd(gsum + tid, cs[tid]); atomicAdd(gsumsq + tid, css[tid]); }
}

__global__ __launch_bounds__(512) void k_gemm_sage(
    const u16* __restrict__ Am, const u16* __restrict__ Ab,
    const u16* __restrict__ WlT, const u16* __restrict__ WrT,
    const float* __restrict__ bl, u16* __restrict__ out,
    float* __restrict__ gsum, float* __restrict__ gsumsq, int n)
{
    __shared__ u16 sA[128 * 128];
    __shared__ u16 sB[128 * 128];
    __shared__ float cs[128], css[128];
    const int tid = threadIdx.x;
    const int rb = blockIdx.x * 128;
    if (tid < 128) { cs[tid] = 0.f; css[tid] = 0.f; }
    const int w = tid >> 6, l15 = tid & 15, grp = (tid & 63) >> 4;
    f4 acc[8] = {};

#pragma unroll
    for (int j = 0; j < 4; j++) {
        int f = j * 512 + tid;
        int r = f >> 4, g = f & 15;
        int row = rb + r;
        uint4 v = {0, 0, 0, 0};
        if (row < n) v = *reinterpret_cast<const uint4*>(Am + (size_t)row * H + g * 8);
        *reinterpret_cast<uint4*>((char*)sA + swz(r, g * 16)) = v;
    }
#pragma unroll
    for (int j = 0; j < 4; j++) {
        int f = j * 512 + tid;
        int r = f >> 4, kb = f & 15;
        uint4 v = *reinterpret_cast<const uint4*>(WlT + r * H + kb * 8);
        *reinterpret_cast<uint4*>((char*)sB + swz(r, kb * 16)) = v;
    }
    __syncthreads();
#pragma unroll
    for (int kc = 0; kc < 4; kc++) {
        bh8 af = *reinterpret_cast<const bh8*>((char*)sA + swz(w * 16 + l15, kc * 64 + grp * 16));
#pragma unroll
        for (int nf = 0; nf < 8; nf++) {
            bh8 bv = *reinterpret_cast<const bh8*>((char*)sB + swz(nf * 16 + l15, kc * 64 + grp * 16));
            acc[nf] = __builtin_amdgcn_mfma_f32_16x16x32_bf16(af, bv, acc[nf], 0, 0, 0);
        }
    }
    __syncthreads();

#pragma unroll
    for (int j = 0; j < 4; j++) {
        int f = j * 512 + tid;
        int r = f >> 4, g = f & 15;
        int row = rb + r;
        uint4 v = {0, 0, 0, 0};
        if (row < n) v = *reinterpret_cast<const uint4*>(Ab + (size_t)row * H + g * 8);
        *reinterpret_cast<uint4*>((char*)sA + swz(r, g * 16)) = v;
    }
#pragma unroll
    for (int j = 0; j < 4; j++) {
        int f = j * 512 + tid;
        int r = f >> 4, kb = f & 15;
        uint4 v = *reinterpret_cast<const uint4*>(WrT + r * H + kb * 8);
        *reinterpret_cast<uint4*>((char*)sB + swz(r, kb * 16)) = v;
    }
    __syncthreads();
#pragma unroll
    for (int kc = 0; kc < 4; kc++) {
        bh8 af = *reinterpret_cast<const bh8*>((char*)sA + swz(w * 16 + l15, kc * 64 + grp * 16));
#pragma unroll
        for (int nf = 0; nf < 8; nf++) {
            bh8 bv = *reinterpret_cast<const bh8*>((char*)sB + swz(nf * 16 + l15, kc * 64 + grp * 16));
            acc[nf] = __builtin_amdgcn_mfma_f32_16x16x32_bf16(af, bv, acc[nf], 0, 0, 0);
        }
    }

#pragma unroll
    for (int nf = 0; nf < 8; nf++) {
        int col = nf * 16 + l15;
        float bc = bl[col];
        float s = 0.f, q = 0.f;
#pragma unroll
        for (int j = 0; j < 4; j++) {
            int row = rb + w * 16 + grp * 4 + j;
            float u = acc[nf][j] + bc;
            if (row < n) {
                out[(size_t)row * H + col] = f2bf(u);
                s += u; q += u * u;
            }
        }
        s += __shfl_xor(s, 16, 64); s += __shfl_xor(s, 32, 64);
        q += __shfl_xor(q, 16, 64); q += __shfl_xor(q, 32, 64);
        if (grp == 0) { atomicAdd(&cs[col], s); atomicAdd(&css[col], q); }
    }
    __syncthreads();
    if (tid < 128) { atomicAdd(gsum + tid, cs[tid]); atomicAdd(gsumsq + tid, css[tid]); }
}

__global__ void k_bnparams(const float* __restrict__ gsum, const float* __restrict__ gsumsq,
                           const float* __restrict__ g, const float* __restrict__ b,
                           float* __restrict__ scale, float* __restrict__ shift, float inv_n)
{
    int c = threadIdx.x;
    float mu = gsum[c] * inv_n;
    float var = fmaxf(gsumsq[c] * inv_n - mu * mu, 0.f);
    float sc = g[c] * rsqrtf(var + BN_EPS);
    scale[c] = sc;
    shift[c] = b[c] - mu * sc;
}

// GCN dense: write xwsp[N][64] (dinv-prescaled bf16; cols 40..63 unwritten pad)
__global__ __launch_bounds__(320) void k_gcn(
    const u16* __restrict__ H2, const float* __restrict__ scale2, const float* __restrict__ shift2,
    const float* __restrict__ Wg, const float* __restrict__ dinv,
    u16* __restrict__ xwsp, int n)
{
    __shared__ float sW[H * OUTD];
    __shared__ float sA[32][H];
    const int tid = threadIdx.x;
#pragma unroll
    for (int j = 0; j < 4; j++) {
        int off = (tid + j * 320) * 4;
        *reinterpret_cast<float4*>(&sW[off]) = ld4(Wg + off);
    }
    const int rb = blockIdx.x * 32;
#pragma unroll
    for (int j = 0; j < 2; j++) {
        int li = tid + j * 320;
        if (li < 512) {
            int r = li >> 4, g = li & 15;
            int row = rb + r;
            float4 v0 = {0.f, 0.f, 0.f, 0.f}, v1 = {0.f, 0.f, 0.f, 0.f};
            if (row < n) {
                uint4 a = *reinterpret_cast<const uint4*>(H2 + (size_t)row * H + g * 8);
                float4 sc0 = ld4(scale2 + g * 8), sc1 = ld4(scale2 + g * 8 + 4);
                float4 sh0 = ld4(shift2 + g * 8), sh1 = ld4(shift2 + g * 8 + 4);
                v0.x = fmaxf(bflo(a.x) * sc0.x + sh0.x, 0.f);
                v0.y = fmaxf(bfhi(a.x) * sc0.y + sh0.y, 0.f);
                v0.z = fmaxf(bflo(a.y) * sc0.z + sh0.z, 0.f);
                v0.w = fmaxf(bfhi(a.y) * sc0.w + sh0.w, 0.f);
                v1.x = fmaxf(bflo(a.z) * sc1.x + sh1.x, 0.f);
                v1.y = fmaxf(bfhi(a.z) * sc1.y + sh1.y, 0.f);
                v1.z = fmaxf(bflo(a.w) * sc1.z + sh1.z, 0.f);
                v1.w = fmaxf(bfhi(a.w) * sc1.w + sh1.w, 0.f);
            }
            *reinterpret_cast<float4*>(&sA[r][g * 8]) = v0;
            *reinterpret_cast<float4*>(&sA[r][g * 8 + 4]) = v1;
        }
    }
    __syncthreads();
    const int c = tid % OUTD;
    const int rg = tid / OUTD;
    float acc[4] = {0.f, 0.f, 0.f, 0.f};
    for (int k = 0; k < H; k++) {
        float w = sW[k * OUTD + c];
#pragma unroll
        for (int i = 0; i < 4; i++) acc[i] += sA[rg + i * 8][k] * w;
    }
#pragma unroll
    for (int i = 0; i < 4; i++) {
        int row = rb + rg + i * 8;
        if (row < n) xwsp[(size_t)row * 64 + c] = f2bf(dinv[row] * acc[i]);
    }
}

extern "C" void kernel_launch(void* const* d_in, const int* in_sizes, int n_in,
                              void* d_out, int out_size, void* d_ws, size_t ws_size,
                              hipStream_t stream)
{
    const float* x     = (const float*)d_in[0];
    const int*   ei    = (const int*)d_in[1];
    const float* w1    = (const float*)d_in[2];
    const float* b1    = (const float*)d_in[3];
    const float* w2    = (const float*)d_in[4];
    const float* b2    = (const float*)d_in[5];
    const float* bn1g  = (const float*)d_in[6];
    const float* bn1b  = (const float*)d_in[7];
    const float* wl    = (const float*)d_in[8];
    const float* bls   = (const float*)d_in[9];
    const float* wr    = (const float*)d_in[10];
    const float* bn2g  = (const float*)d_in[11];
    const float* bn2b  = (const float*)d_in[12];
    const float* wg    = (const float*)d_in[13];
    const float* bg    = (const float*)d_in[14];

    const int N = in_sizes[0] / H;
    const int E = in_sizes[1] / 2;
    const int* src = ei;
    const int* dst = ei + E;
    float* outp = (float*)d_out;

    const int NRANGE = (N + RSIZE - 1) >> RBITS;

    u16* P0   = (u16*)d_ws;
    u16* P1   = P0 + (size_t)N * H;
    u16* P2   = P1 + (size_t)N * H;
    u16* xwsp = P2 + (size_t)N * H;              // N*64 bf16 (128B rows, padded)
    float* dinv = (float*)(xwsp + (size_t)N * 64);
    float* st   = dinv + N;
    int*  deg   = (int*)(st + 1024);
    int*  cursor= deg + N;
    int*  bsum  = cursor + N;
    int*  csr   = bsum + 1024;
    u16* wt1 = (u16*)(csr + E);
    u16* wt2 = wt1 + 16384;
    u16* wtl = wt2 + 16384;
    u16* wtr = wtl + 16384;
    u32* partial = (u32*)P0;
    float* sum1 = st,        *sumsq1 = st + 128;
    float* sum2 = st + 256,  *sumsq2 = st + 384;
    float* scale1 = st + 512, *shift1 = st + 640;
    float* scale2 = st + 768, *shift2 = st + 896;

    hipMemsetAsync(st, 0, 1024 * sizeof(float), stream);

    const int nb = (N + 1023) / 1024;
    const int total8 = N * H / 8;
    const int csrblk = NXCD * NB;

    k_prep<<<256, 256, 0, stream>>>(w1, w2, wl, wr, wt1, wt2, wtl, wtr);
    k_hist2<<<csrblk, 256, 0, stream>>>(dst, partial, E, NRANGE);
    k_scan1<<<nb, 256, 0, stream>>>(partial, deg, cursor, bsum, N);
    k_scan2<<<1, 256, 0, stream>>>(bsum, nb);
    k_scan3<<<(N + 255) / 256, 256, 0, stream>>>(cursor, bsum, deg, dinv, N);
    k_fill2<<<csrblk, 256, 0, stream>>>(src, dst, cursor, partial, csr, E, NRANGE);

    k_xbf<<<(total8 + 255) / 256, 256, 0, stream>>>(x, P2, total8);

    const int aggblk4 = (N + 15) / 16;
    const int gblocks = (N + 127) / 128;

    // ---- layer 1 ----
    k_agg1<<<aggblk4, 256, 0, stream>>>(P2, csr, cursor, deg, P0, N);
    k_gemm_film<<<gblocks, 512, 0, stream>>>(P0, wt1, b1, wt2, b2, P2, sum1, sumsq1, N);
    k_bnparams<<<1, 128, 0, stream>>>(sum1, sumsq1, bn1g, bn1b, scale1, shift1, 1.0f / N);

    // ---- layer 2 ----
    k_act1<<<(total8 + 255) / 256, 256, 0, stream>>>(P2, scale1, shift1, P0, total8);
    k_agg2<<<aggblk4, 256, 0, stream>>>(P0, csr, cursor, deg, P1, N);
    k_gemm_sage<<<gblocks, 512, 0, stream>>>(P1, P0, wtl, wtr, bls, P1, sum2, sumsq2, N);
    k_bnparams<<<1, 128, 0, stream>>>(sum2, sumsq2, bn2g, bn2b, scale2, shift2, 1.0f / N);

    // ---- layer 3 ----
    k_gcn<<<(N + 31) / 32, 320, 0, stream>>>(P1, scale2, shift2, wg, dinv, xwsp, N);
    k_agg3<<<aggblk4, 256, 0, stream>>>(xwsp, dinv, csr, cursor, deg, bg, outp, N);
}

// Round 17
// 393.574 us; speedup vs baseline: 1.1060x; 1.0529x over previous
//
#include <hip/hip_runtime.h>
#include <math.h>

#define H 128
#define OUTD 40
#define BN_EPS 1e-5f
#define NEG_SLOPE 0.01f
#define RBITS 13
#define RSIZE 8192
#define NB 128           // edge chunks per range

typedef __attribute__((ext_vector_type(8))) short bh8;
typedef __attribute__((ext_vector_type(4))) float f4;
typedef unsigned short u16;
typedef unsigned int u32;

__device__ __forceinline__ float4 ld4(const float* p) {
    return *reinterpret_cast<const float4*>(p);
}
__device__ __forceinline__ u16 f2bf(float f) {
    unsigned int u = __float_as_uint(f);
    u += 0x7fffu + ((u >> 16) & 1u);          // RNE
    return (u16)(u >> 16);
}
__device__ __forceinline__ float bflo(unsigned d) { return __uint_as_float(d << 16); }
__device__ __forceinline__ float bfhi(unsigned d) { return __uint_as_float(d & 0xffff0000u); }
__device__ __forceinline__ unsigned pk(float a, float b) {
    return (unsigned)f2bf(a) | ((unsigned)f2bf(b) << 16);
}
__device__ __forceinline__ int swz(int row, int byteInRow) {
    return row * 256 + (byteInRow ^ ((row & 7) << 4));
}

// ================= x -> bf16 =================
__global__ __launch_bounds__(256) void k_xbf(
    const float* __restrict__ x, u16* __restrict__ xb, int total8)
{
    int i = blockIdx.x * 256 + threadIdx.x;
    if (i >= total8) return;
    float4 a = ld4(x + (size_t)i * 8);
    float4 b = ld4(x + (size_t)i * 8 + 4);
    uint4 o;
    o.x = pk(a.x, a.y); o.y = pk(a.z, a.w);
    o.z = pk(b.x, b.y); o.w = pk(b.z, b.w);
    *reinterpret_cast<uint4*>(xb + (size_t)i * 8) = o;
}

// ================= weight prep: WT[c][k] = bf16(W[k][c]) =================
__global__ __launch_bounds__(256) void k_prep(
    const float* __restrict__ w1, const float* __restrict__ w2,
    const float* __restrict__ wl, const float* __restrict__ wr,
    u16* __restrict__ wt1, u16* __restrict__ wt2,
    u16* __restrict__ wtl, u16* __restrict__ wtr)
{
    int id = blockIdx.x * 256 + threadIdx.x;
    int sel = id >> 14;
    int o = id & 16383;
    int c = o >> 7, k = o & 127;
    const float* w = (sel == 0) ? w1 : (sel == 1) ? w2 : (sel == 2) ? wl : wr;
    u16* wt = (sel == 0) ? wt1 : (sel == 1) ? wt2 : (sel == 2) ? wtl : wtr;
    wt[o] = f2bf(w[k * H + c]);
}

// ================= CSR build (atomic-free, occupancy-sized) =================
// Block (r, bb): LDS-histogram chunk bb's dst within range r (8192 bins,
// 16KB packed u16), plain coalesced partial stores. Grid = nrange*NB.
__global__ __launch_bounds__(256) void k_hist2(
    const int* __restrict__ dst, u32* __restrict__ partial, int E)
{
    __shared__ u32 hcnt[RSIZE / 2];           // 16KB
    const int tid = threadIdx.x;
    const int r = blockIdx.x / NB, bb = blockIdx.x % NB;
    for (int t = tid; t < RSIZE / 2; t += 256) hcnt[t] = 0;
    __syncthreads();
    const int lo = r << RBITS;
    const int chunk = (E + NB - 1) / NB;
    const int s0 = bb * chunk;
    const int s1 = min(E, s0 + chunk);
    for (int e = s0 + tid; e < s1; e += 256) {
        unsigned local = (unsigned)(dst[e] - lo);
        if (local < (unsigned)RSIZE)
            atomicAdd(&hcnt[local >> 1], 1u << ((local & 1) << 4));
    }
    __syncthreads();
    u32* out = partial + ((size_t)blockIdx.x << 12);
    for (int t = tid; t < RSIZE / 2; t += 256) out[t] = hcnt[t];
}

// scan1: sum NB chunk-partials -> deg; rewrite partials as exclusive chunk-prefix;
// block-local exclusive scan of deg (1024/block) -> cursor
__global__ __launch_bounds__(256) void k_scan1(
    u32* __restrict__ partial, int* __restrict__ deg,
    int* __restrict__ cursor, int* __restrict__ bsum, int n)
{
    __shared__ int sums[256];
    const int tid = threadIdx.x;
    const int idx = blockIdx.x * 1024 + tid * 4;
    const int r = idx >> RBITS;
    const int jw = (idx & (RSIZE - 1)) >> 1;
    uint2 acc = {0u, 0u};
    for (int bb = 0; bb < NB; bb++) {
        u32* p = partial + (((size_t)(r * NB + bb)) << 12) + jw;
        uint2 w = *reinterpret_cast<uint2*>(p);
        *reinterpret_cast<uint2*>(p) = acc;
        acc.x += w.x; acc.y += w.y;
    }
    int4 v;
    v.x = (int)(acc.x & 0xFFFFu); v.y = (int)(acc.x >> 16);
    v.z = (int)(acc.y & 0xFFFFu); v.w = (int)(acc.y >> 16);
    if (idx + 0 >= n) v.x = 0;
    if (idx + 1 >= n) v.y = 0;
    if (idx + 2 >= n) v.z = 0;
    if (idx + 3 >= n) v.w = 0;
    if (idx + 3 < n) *reinterpret_cast<int4*>(deg + idx) = v;
    else {
        if (idx + 0 < n) deg[idx + 0] = v.x;
        if (idx + 1 < n) deg[idx + 1] = v.y;
        if (idx + 2 < n) deg[idx + 2] = v.z;
        if (idx + 3 < n) deg[idx + 3] = v.w;
    }
    int t = v.x + v.y + v.z + v.w;
    sums[tid] = t;
    __syncthreads();
    for (int off = 1; off < 256; off <<= 1) {
        int other = (tid >= off) ? sums[tid - off] : 0;
        __syncthreads();
        sums[tid] += other;
        __syncthreads();
    }
    int incl = sums[tid];
    int excl = incl - t;
    if (tid == 255) bsum[blockIdx.x] = incl;
    int c0 = excl, c1 = c0 + v.x, c2 = c1 + v.y, c3 = c2 + v.z;
    if (idx + 3 < n) {
        int4 o = {c0, c1, c2, c3};
        *reinterpret_cast<int4*>(cursor + idx) = o;
    } else {
        if (idx + 0 < n) cursor[idx + 0] = c0;
        if (idx + 1 < n) cursor[idx + 1] = c1;
        if (idx + 2 < n) cursor[idx + 2] = c2;
        if (idx + 3 < n) cursor[idx + 3] = c3;
    }
}

__global__ void k_scan2(int* __restrict__ bsum, int nb)
{
    __shared__ int s[1024];
    const int tid = threadIdx.x;
    for (int i = tid; i < nb; i += blockDim.x) s[i] = bsum[i];
    __syncthreads();
    if (tid == 0) {
        int acc = 0;
        for (int i = 0; i < nb; i++) { int t = s[i]; s[i] = acc; acc += t; }
    }
    __syncthreads();
    for (int i = tid; i < nb; i += blockDim.x) bsum[i] = s[i];
}

__global__ __launch_bounds__(256) void k_scan3(
    int* __restrict__ cursor, const int* __restrict__ bsum,
    const int* __restrict__ deg, float* __restrict__ dinv, int n)
{
    int i = blockIdx.x * 256 + threadIdx.x;
    if (i < n) {
        cursor[i] += bsum[i >> 10];
        dinv[i] = rsqrtf((float)deg[i] + 1.0f);
    }
}

// fill: recount chunk in LDS for within-chunk rank; slot = cursor + prefix + rank
__global__ __launch_bounds__(256) void k_fill2(
    const int* __restrict__ src, const int* __restrict__ dst,
    const int* __restrict__ cursor, const u32* __restrict__ partial,
    int* __restrict__ csr, int E)
{
    __shared__ u32 rcnt[RSIZE / 2];
    const int tid = threadIdx.x;
    const int r = blockIdx.x / NB, bb = blockIdx.x % NB;
    for (int t = tid; t < RSIZE / 2; t += 256) rcnt[t] = 0;
    __syncthreads();
    const int lo = r << RBITS;
    const int chunk = (E + NB - 1) / NB;
    const int s0 = bb * chunk;
    const int s1 = min(E, s0 + chunk);
    const u32* pref = partial + ((size_t)blockIdx.x << 12);
    for (int e = s0 + tid; e < s1; e += 256) {
        int d = dst[e];
        unsigned local = (unsigned)(d - lo);
        if (local < (unsigned)RSIZE) {
            unsigned sh = (local & 1) << 4;
            unsigned old = atomicAdd(&rcnt[local >> 1], 1u << sh);
            unsigned rank = (old >> sh) & 0xFFFFu;
            unsigned pfx = (pref[local >> 1] >> sh) & 0xFFFFu;
            csr[cursor[d] + (int)pfx + (int)rank] = src[e];
        }
    }
}

// ================= gather aggregations (bf16 features) =================
__global__ __launch_bounds__(256) void k_agg1(
    const u16* __restrict__ xb, const int* __restrict__ csr,
    const int* __restrict__ cursor, const int* __restrict__ deg,
    u16* __restrict__ out, int n)
{
    int wave = (blockIdx.x * 256 + threadIdx.x) >> 6;
    int lane = threadIdx.x & 63;
    int row = wave * 4 + (lane >> 4);
    if (row >= n) return;
    int g = lane & 15;
    int start = cursor[row];
    int end = start + deg[row];
    float acc[8] = {0.f, 0.f, 0.f, 0.f, 0.f, 0.f, 0.f, 0.f};
    int i = start;
    for (; i + 4 <= end; i += 4) {
        int s0 = csr[i], s1 = csr[i + 1], s2 = csr[i + 2], s3 = csr[i + 3];
        uint4 a = *reinterpret_cast<const uint4*>(xb + (size_t)s0 * H + g * 8);
        uint4 b = *reinterpret_cast<const uint4*>(xb + (size_t)s1 * H + g * 8);
        uint4 c = *reinterpret_cast<const uint4*>(xb + (size_t)s2 * H + g * 8);
        uint4 d = *reinterpret_cast<const uint4*>(xb + (size_t)s3 * H + g * 8);
        acc[0] += (bflo(a.x) + bflo(b.x)) + (bflo(c.x) + bflo(d.x));
        acc[1] += (bfhi(a.x) + bfhi(b.x)) + (bfhi(c.x) + bfhi(d.x));
        acc[2] += (bflo(a.y) + bflo(b.y)) + (bflo(c.y) + bflo(d.y));
        acc[3] += (bfhi(a.y) + bfhi(b.y)) + (bfhi(c.y) + bfhi(d.y));
        acc[4] += (bflo(a.z) + bflo(b.z)) + (bflo(c.z) + bflo(d.z));
        acc[5] += (bfhi(a.z) + bfhi(b.z)) + (bfhi(c.z) + bfhi(d.z));
        acc[6] += (bflo(a.w) + bflo(b.w)) + (bflo(c.w) + bflo(d.w));
        acc[7] += (bfhi(a.w) + bfhi(b.w)) + (bfhi(c.w) + bfhi(d.w));
    }
    for (; i < end; i++) {
        int s = csr[i];
        uint4 a = *reinterpret_cast<const uint4*>(xb + (size_t)s * H + g * 8);
        acc[0] += bflo(a.x); acc[1] += bfhi(a.x);
        acc[2] += bflo(a.y); acc[3] += bfhi(a.y);
        acc[4] += bflo(a.z); acc[5] += bfhi(a.z);
        acc[6] += bflo(a.w); acc[7] += bfhi(a.w);
    }
    uint4 o;
    o.x = pk(acc[0], acc[1]); o.y = pk(acc[2], acc[3]);
    o.z = pk(acc[4], acc[5]); o.w = pk(acc[6], acc[7]);
    *reinterpret_cast<uint4*>(out + (size_t)row * H + g * 8) = o;
}

// act1h = bf16(relu(affine1(h))), elementwise
__global__ __launch_bounds__(256) void k_act1(
    const u16* __restrict__ hb, const float* __restrict__ scale, const float* __restrict__ shift,
    u16* __restrict__ out, int total8)
{
    int i = blockIdx.x * 256 + threadIdx.x;
    if (i >= total8) return;
    int g = i & 15;
    uint4 a = *reinterpret_cast<const uint4*>(hb + (size_t)i * 8);
    float4 sc0 = ld4(scale + g * 8), sc1 = ld4(scale + g * 8 + 4);
    float4 sh0 = ld4(shift + g * 8), sh1 = ld4(shift + g * 8 + 4);
    float e0 = fmaxf(bflo(a.x) * sc0.x + sh0.x, 0.f);
    float e1 = fmaxf(bfhi(a.x) * sc0.y + sh0.y, 0.f);
    float e2 = fmaxf(bflo(a.y) * sc0.z + sh0.z, 0.f);
    float e3 = fmaxf(bfhi(a.y) * sc0.w + sh0.w, 0.f);
    float e4 = fmaxf(bflo(a.z) * sc1.x + sh1.x, 0.f);
    float e5 = fmaxf(bfhi(a.z) * sc1.y + sh1.y, 0.f);
    float e6 = fmaxf(bflo(a.w) * sc1.z + sh1.z, 0.f);
    float e7 = fmaxf(bfhi(a.w) * sc1.w + sh1.w, 0.f);
    uint4 o;
    o.x = pk(e0, e1); o.y = pk(e2, e3); o.z = pk(e4, e5); o.w = pk(e6, e7);
    *reinterpret_cast<uint4*>(out + (size_t)i * 8) = o;
}

__global__ __launch_bounds__(256) void k_agg2(
    const u16* __restrict__ ab, const int* __restrict__ csr,
    const int* __restrict__ cursor, const int* __restrict__ deg,
    u16* __restrict__ out, int n)
{
    int wave = (blockIdx.x * 256 + threadIdx.x) >> 6;
    int lane = threadIdx.x & 63;
    int row = wave * 4 + (lane >> 4);
    if (row >= n) return;
    int g = lane & 15;
    int dg = deg[row];
    int start = cursor[row];
    int end = start + dg;
    float acc[8] = {0.f, 0.f, 0.f, 0.f, 0.f, 0.f, 0.f, 0.f};
    int i = start;
    for (; i + 4 <= end; i += 4) {
        int s0 = csr[i], s1 = csr[i + 1], s2 = csr[i + 2], s3 = csr[i + 3];
        uint4 a = *reinterpret_cast<const uint4*>(ab + (size_t)s0 * H + g * 8);
        uint4 b = *reinterpret_cast<const uint4*>(ab + (size_t)s1 * H + g * 8);
        uint4 c = *reinterpret_cast<const uint4*>(ab + (size_t)s2 * H + g * 8);
        uint4 d = *reinterpret_cast<const uint4*>(ab + (size_t)s3 * H + g * 8);
        acc[0] += (bflo(a.x) + bflo(b.x)) + (bflo(c.x) + bflo(d.x));
        acc[1] += (bfhi(a.x) + bfhi(b.x)) + (bfhi(c.x) + bfhi(d.x));
        acc[2] += (bflo(a.y) + bflo(b.y)) + (bflo(c.y) + bflo(d.y));
        acc[3] += (bfhi(a.y) + bfhi(b.y)) + (bfhi(c.y) + bfhi(d.y));
        acc[4] += (bflo(a.z) + bflo(b.z)) + (bflo(c.z) + bflo(d.z));
        acc[5] += (bfhi(a.z) + bfhi(b.z)) + (bfhi(c.z) + bfhi(d.z));
        acc[6] += (bflo(a.w) + bflo(b.w)) + (bflo(c.w) + bflo(d.w));
        acc[7] += (bfhi(a.w) + bfhi(b.w)) + (bfhi(c.w) + bfhi(d.w));
    }
    for (; i < end; i++) {
        int s = csr[i];
        uint4 a = *reinterpret_cast<const uint4*>(ab + (size_t)s * H + g * 8);
        acc[0] += bflo(a.x); acc[1] += bfhi(a.x);
        acc[2] += bflo(a.y); acc[3] += bfhi(a.y);
        acc[4] += bflo(a.z); acc[5] += bfhi(a.z);
        acc[6] += bflo(a.w); acc[7] += bfhi(a.w);
    }
    float idv = 1.0f / fmaxf((float)dg, 1.0f);
    uint4 o;
    o.x = pk(acc[0] * idv, acc[1] * idv); o.y = pk(acc[2] * idv, acc[3] * idv);
    o.z = pk(acc[4] * idv, acc[5] * idv); o.w = pk(acc[6] * idv, acc[7] * idv);
    *reinterpret_cast<uint4*>(out + (size_t)row * H + g * 8) = o;
}

// GCN gather + self-loop + bias + log-softmax.
// xwsp[N][64] bf16 (128B rows, cols 40..63 pad). Wave = 4 rows x 16 lanes;
// lane g holds cols g*4..g*4+3 (uint2 per neighbor). Lanes g>=10 masked.
__global__ __launch_bounds__(256) void k_agg3(
    const u16* __restrict__ xwsp, const float* __restrict__ dinv,
    const int* __restrict__ csr, const int* __restrict__ cursor, const int* __restrict__ deg,
    const float* __restrict__ bias, float* __restrict__ outp, int n)
{
    int wave = (blockIdx.x * 256 + threadIdx.x) >> 6;
    int lane = threadIdx.x & 63;
    int row = wave * 4 + (lane >> 4);
    if (row >= n) return;
    int g = lane & 15;
    bool act = g < 10;
    const u16* base = xwsp + g * 4;
    int start = cursor[row];
    int end = start + deg[row];
    float a0 = 0.f, a1 = 0.f, a2 = 0.f, a3 = 0.f;
    int i = start;
    for (; i + 4 <= end; i += 4) {
        int s0 = csr[i], s1 = csr[i + 1], s2 = csr[i + 2], s3 = csr[i + 3];
        uint2 u0 = *reinterpret_cast<const uint2*>(base + (size_t)s0 * 64);
        uint2 u1 = *reinterpret_cast<const uint2*>(base + (size_t)s1 * 64);
        uint2 u2 = *reinterpret_cast<const uint2*>(base + (size_t)s2 * 64);
        uint2 u3 = *reinterpret_cast<const uint2*>(base + (size_t)s3 * 64);
        a0 += (bflo(u0.x) + bflo(u1.x)) + (bflo(u2.x) + bflo(u3.x));
        a1 += (bfhi(u0.x) + bfhi(u1.x)) + (bfhi(u2.x) + bfhi(u3.x));
        a2 += (bflo(u0.y) + bflo(u1.y)) + (bflo(u2.y) + bflo(u3.y));
        a3 += (bfhi(u0.y) + bfhi(u1.y)) + (bfhi(u2.y) + bfhi(u3.y));
    }
    for (; i < end; i++) {
        uint2 u = *reinterpret_cast<const uint2*>(base + (size_t)csr[i] * 64);
        a0 += bflo(u.x); a1 += bfhi(u.x);
        a2 += bflo(u.y); a3 += bfhi(u.y);
    }
    uint2 sf = *reinterpret_cast<const uint2*>(base + (size_t)row * 64);
    float di = dinv[row];
    float4 bb = {0.f, 0.f, 0.f, 0.f};
    if (act) bb = ld4(bias + g * 4);
    float v0 = di * (a0 + bflo(sf.x)) + bb.x;
    float v1 = di * (a1 + bfhi(sf.x)) + bb.y;
    float v2 = di * (a2 + bflo(sf.y)) + bb.z;
    float v3 = di * (a3 + bfhi(sf.y)) + bb.w;
    float m = act ? fmaxf(fmaxf(v0, v1), fmaxf(v2, v3)) : -INFINITY;
#pragma unroll
    for (int s = 1; s < 16; s <<= 1) m = fmaxf(m, __shfl_xor(m, s, 64));
    float e0 = act ? expf(v0 - m) : 0.f;
    float e1 = act ? expf(v1 - m) : 0.f;
    float e2 = act ? expf(v2 - m) : 0.f;
    float e3 = act ? expf(v3 - m) : 0.f;
    float sum = (e0 + e1) + (e2 + e3);
#pragma unroll
    for (int s = 1; s < 16; s <<= 1) sum += __shfl_xor(sum, s, 64);
    float l = logf(sum) + m;
    if (act) {
        float4 o = {v0 - l, v1 - l, v2 - l, v3 - l};
        *reinterpret_cast<float4*>(outp + (size_t)row * OUTD + g * 4) = o;
    }
}

// ================= MFMA dense layers (128-row tiles, 512 threads) =================
__global__ __launch_bounds__(512) void k_gemm_film(
    const u16* __restrict__ A, const u16* __restrict__ W1T, const float* __restrict__ b1,
    const u16* __restrict__ W2T, const float* __restrict__ b2,
    u16* __restrict__ out, float* __restrict__ gsum, float* __restrict__ gsumsq, int n)
{
    __shared__ u16 sA[128 * 128];
    __shared__ u16 sB[128 * 128];
    __shared__ float cs[128], css[128];
    const int tid = threadIdx.x;
    const int rb = blockIdx.x * 128;
    if (tid < 128) { cs[tid] = 0.f; css[tid] = 0.f; }
    const int w = tid >> 6, l15 = tid & 15, grp = (tid & 63) >> 4;

#pragma unroll
    for (int j = 0; j < 4; j++) {
        int f = j * 512 + tid;
        int r = f >> 4, g = f & 15;
        int row = rb + r;
        uint4 v = {0, 0, 0, 0};
        if (row < n) v = *reinterpret_cast<const uint4*>(A + (size_t)row * H + g * 8);
        *reinterpret_cast<uint4*>((char*)sA + swz(r, g * 16)) = v;
    }
#pragma unroll
    for (int j = 0; j < 4; j++) {
        int f = j * 512 + tid;
        int r = f >> 4, kb = f & 15;
        uint4 v = *reinterpret_cast<const uint4*>(W1T + r * H + kb * 8);
        *reinterpret_cast<uint4*>((char*)sB + swz(r, kb * 16)) = v;
    }
    __syncthreads();
    f4 acc[8] = {};
#pragma unroll
    for (int kc = 0; kc < 4; kc++) {
        bh8 af = *reinterpret_cast<const bh8*>((char*)sA + swz(w * 16 + l15, kc * 64 + grp * 16));
#pragma unroll
        for (int nf = 0; nf < 8; nf++) {
            bh8 bv = *reinterpret_cast<const bh8*>((char*)sB + swz(nf * 16 + l15, kc * 64 + grp * 16));
            acc[nf] = __builtin_amdgcn_mfma_f32_16x16x32_bf16(af, bv, acc[nf], 0, 0, 0);
        }
    }
    __syncthreads();

#pragma unroll
    for (int nf = 0; nf < 8; nf++) {
        int col = nf * 16 + l15;
        float bc = b1[col];
#pragma unroll
        for (int j = 0; j < 4; j++) {
            int row = w * 16 + grp * 4 + j;
            float u = acc[nf][j] + bc;
            u = u > 0.f ? u : NEG_SLOPE * u;
            *reinterpret_cast<u16*>((char*)sA + swz(row, col * 2)) = f2bf(u);
        }
        acc[nf] = f4{0.f, 0.f, 0.f, 0.f};
    }
#pragma unroll
    for (int j = 0; j < 4; j++) {
        int f = j * 512 + tid;
        int r = f >> 4, kb = f & 15;
        uint4 v = *reinterpret_cast<const uint4*>(W2T + r * H + kb * 8);
        *reinterpret_cast<uint4*>((char*)sB + swz(r, kb * 16)) = v;
    }
    __syncthreads();

#pragma unroll
    for (int kc = 0; kc < 4; kc++) {
        bh8 af = *reinterpret_cast<const bh8*>((char*)sA + swz(w * 16 + l15, kc * 64 + grp * 16));
#pragma unroll
        for (int nf = 0; nf < 8; nf++) {
            bh8 bv = *reinterpret_cast<const bh8*>((char*)sB + swz(nf * 16 + l15, kc * 64 + grp * 16));
            acc[nf] = __builtin_amdgcn_mfma_f32_16x16x32_bf16(af, bv, acc[nf], 0, 0, 0);
        }
    }

#pragma unroll
    for (int nf = 0; nf < 8; nf++) {
        float bc = b2[nf * 16 + l15];
#pragma unroll
        for (int j = 0; j < 4; j++) acc[nf][j] += bc;
    }
    float inv[4];
#pragma unroll
    for (int j = 0; j < 4; j++) {
        float ss = 0.f;
#pragma unroll
        for (int nf = 0; nf < 8; nf++) ss += acc[nf][j] * acc[nf][j];
        ss += __shfl_xor(ss, 1, 64); ss += __shfl_xor(ss, 2, 64);
        ss += __shfl_xor(ss, 4, 64); ss += __shfl_xor(ss, 8, 64);
        inv[j] = 1.0f / fmaxf(sqrtf(ss), 1e-12f);
    }
#pragma unroll
    for (int nf = 0; nf < 8; nf++) {
        int col = nf * 16 + l15;
        float s = 0.f, q = 0.f;
#pragma unroll
        for (int j = 0; j < 4; j++) {
            int row = rb + w * 16 + grp * 4 + j;
            float u = acc[nf][j] * inv[j];
            if (row < n) {
                out[(size_t)row * H + col] = f2bf(u);
                s += u; q += u * u;
            }
        }
        s += __shfl_xor(s, 16, 64); s += __shfl_xor(s, 32, 64);
        q += __shfl_xor(q, 16, 64); q += __shfl_xor(q, 32, 64);
        if (grp == 0) { atomicAdd(&cs[col], s); atomicAdd(&css[col], q); }
    }
    __syncthreads();
    if (tid < 128) { atomicAdd(gsum + tid, cs[tid]); atomicAdd(gsumsq + tid, css[tid]); }
}

__global__ __launch_bounds__(512) void k_gemm_sage(
    const u16* __restrict__ Am, const u16* __restrict__ Ab,
    const u16* __restrict__ WlT, const u16* __restrict__ WrT,
    const float* __restrict__ bl, u16* __restrict__ out,
    float* __restrict__ gsum, float* __restrict__ gsumsq, int n)
{
    __shared__ u16 sA[128 * 128];
    __shared__ u16 sB[128 * 128];
    __shared__ float cs[128], css[128];
    const int tid = threadIdx.x;
    const int rb = blockIdx.x * 128;
    if (tid < 128) { cs[tid] = 0.f; css[tid] = 0.f; }
    const int w = tid >> 6, l15 = tid & 15, grp = (tid & 63) >> 4;
    f4 acc[8] = {};

#pragma unroll
    for (int j = 0; j < 4; j++) {
        int f = j * 512 + tid;
        int r = f >> 4, g = f & 15;
        int row = rb + r;
        uint4 v = {0, 0, 0, 0};
        if (row < n) v = *reinterpret_cast<const uint4*>(Am + (size_t)row * H + g * 8);
        *reinterpret_cast<uint4*>((char*)sA + swz(r, g * 16)) = v;
    }
#pragma unroll
    for (int j = 0; j < 4; j++) {
        int f = j * 512 + tid;
        int r = f >> 4, kb = f & 15;
        uint4 v = *reinterpret_cast<const uint4*>(WlT + r * H + kb * 8);
        *reinterpret_cast<uint4*>((char*)sB + swz(r, kb * 16)) = v;
    }
    __syncthreads();
#pragma unroll
    for (int kc = 0; kc < 4; kc++) {
        bh8 af = *reinterpret_cast<const bh8*>((char*)sA + swz(w * 16 + l15, kc * 64 + grp * 16));
#pragma unroll
        for (int nf = 0; nf < 8; nf++) {
            bh8 bv = *reinterpret_cast<const bh8*>((char*)sB + swz(nf * 16 + l15, kc * 64 + grp * 16));
            acc[nf] = __builtin_amdgcn_mfma_f32_16x16x32_bf16(af, bv, acc[nf], 0, 0, 0);
        }
    }
    __syncthreads();

#pragma unroll
    for (int j = 0; j < 4; j++) {
        int f = j * 512 + tid;
        int r = f >> 4, g = f & 15;
        int row = rb + r;
        uint4 v = {0, 0, 0, 0};
        if (row < n) v = *reinterpret_cast<const uint4*>(Ab + (size_t)row * H + g * 8);
        *reinterpret_cast<uint4*>((char*)sA + swz(r, g * 16)) = v;
    }
#pragma unroll
    for (int j = 0; j < 4; j++) {
        int f = j * 512 + tid;
        int r = f >> 4, kb = f & 15;
        uint4 v = *reinterpret_cast<const uint4*>(WrT + r * H + kb * 8);
        *reinterpret_cast<uint4*>((char*)sB + swz(r, kb * 16)) = v;
    }
    __syncthreads();
#pragma unroll
    for (int kc = 0; kc < 4; kc++) {
        bh8 af = *reinterpret_cast<const bh8*>((char*)sA + swz(w * 16 + l15, kc * 64 + grp * 16));
#pragma unroll
        for (int nf = 0; nf < 8; nf++) {
            bh8 bv = *reinterpret_cast<const bh8*>((char*)sB + swz(nf * 16 + l15, kc * 64 + grp * 16));
            acc[nf] = __builtin_amdgcn_mfma_f32_16x16x32_bf16(af, bv, acc[nf], 0, 0, 0);
        }
    }

#pragma unroll
    for (int nf = 0; nf < 8; nf++) {
        int col = nf * 16 + l15;
        float bc = bl[col];
        float s = 0.f, q = 0.f;
#pragma unroll
        for (int j = 0; j < 4; j++) {
            int row = rb + w * 16 + grp * 4 + j;
            float u = acc[nf][j] + bc;
            if (row < n) {
                out[(size_t)row * H + col] = f2bf(u);
                s += u; q += u * u;
            }
        }
        s += __shfl_xor(s, 16, 64); s += __shfl_xor(s, 32, 64);
        q += __shfl_xor(q, 16, 64); q += __shfl_xor(q, 32, 64);
        if (grp == 0) { atomicAdd(&cs[col], s); atomicAdd(&css[col], q); }
    }
    __syncthreads();
    if (tid < 128) { atomicAdd(gsum + tid, cs[tid]); atomicAdd(gsumsq + tid, css[tid]); }
}

__global__ void k_bnparams(const float* __restrict__ gsum, const float* __restrict__ gsumsq,
                           const float* __restrict__ g, const float* __restrict__ b,
                           float* __restrict__ scale, float* __restrict__ shift, float inv_n)
{
    int c = threadIdx.x;
    float mu = gsum[c] * inv_n;
    float var = fmaxf(gsumsq[c] * inv_n - mu * mu, 0.f);
    float sc = g[c] * rsqrtf(var + BN_EPS);
    scale[c] = sc;
    shift[c] = b[c] - mu * sc;
}

// GCN dense: write xwsp[N][64] (dinv-prescaled bf16; cols 40..63 unwritten pad)
__global__ __launch_bounds__(320) void k_gcn(
    const u16* __restrict__ H2, const float* __restrict__ scale2, const float* __restrict__ shift2,
    const float* __restrict__ Wg, const float* __restrict__ dinv,
    u16* __restrict__ xwsp, int n)
{
    __shared__ float sW[H * OUTD];
    __shared__ float sA[32][H];
    const int tid = threadIdx.x;
#pragma unroll
    for (int j = 0; j < 4; j++) {
        int off = (tid + j * 320) * 4;
        *reinterpret_cast<float4*>(&sW[off]) = ld4(Wg + off);
    }
    const int rb = blockIdx.x * 32;
#pragma unroll
    for (int j = 0; j < 2; j++) {
        int li = tid + j * 320;
        if (li < 512) {
            int r = li >> 4, g = li & 15;
            int row = rb + r;
            float4 v0 = {0.f, 0.f, 0.f, 0.f}, v1 = {0.f, 0.f, 0.f, 0.f};
            if (row < n) {
                uint4 a = *reinterpret_cast<const uint4*>(H2 + (size_t)row * H + g * 8);
                float4 sc0 = ld4(scale2 + g * 8), sc1 = ld4(scale2 + g * 8 + 4);
                float4 sh0 = ld4(shift2 + g * 8), sh1 = ld4(shift2 + g * 8 + 4);
                v0.x = fmaxf(bflo(a.x) * sc0.x + sh0.x, 0.f);
                v0.y = fmaxf(bfhi(a.x) * sc0.y + sh0.y, 0.f);
                v0.z = fmaxf(bflo(a.y) * sc0.z + sh0.z, 0.f);
                v0.w = fmaxf(bfhi(a.y) * sc0.w + sh0.w, 0.f);
                v1.x = fmaxf(bflo(a.z) * sc1.x + sh1.x, 0.f);
                v1.y = fmaxf(bfhi(a.z) * sc1.y + sh1.y, 0.f);
                v1.z = fmaxf(bflo(a.w) * sc1.z + sh1.z, 0.f);
                v1.w = fmaxf(bfhi(a.w) * sc1.w + sh1.w, 0.f);
            }
            *reinterpret_cast<float4*>(&sA[r][g * 8]) = v0;
            *reinterpret_cast<float4*>(&sA[r][g * 8 + 4]) = v1;
        }
    }
    __syncthreads();
    const int c = tid % OUTD;
    const int rg = tid / OUTD;
    float acc[4] = {0.f, 0.f, 0.f, 0.f};
    for (int k = 0; k < H; k++) {
        float w = sW[k * OUTD + c];
#pragma unroll
        for (int i = 0; i < 4; i++) acc[i] += sA[rg + i * 8][k] * w;
    }
#pragma unroll
    for (int i = 0; i < 4; i++) {
        int row = rb + rg + i * 8;
        if (row < n) xwsp[(size_t)row * 64 + c] = f2bf(dinv[row] * acc[i]);
    }
}

extern "C" void kernel_launch(void* const* d_in, const int* in_sizes, int n_in,
                              void* d_out, int out_size, void* d_ws, size_t ws_size,
                              hipStream_t stream)
{
    const float* x     = (const float*)d_in[0];
    const int*   ei    = (const int*)d_in[1];
    const float* w1    = (const float*)d_in[2];
    const float* b1    = (const float*)d_in[3];
    const float* w2    = (const float*)d_in[4];
    const float* b2    = (const float*)d_in[5];
    const float* bn1g  = (const float*)d_in[6];
    const float* bn1b  = (const float*)d_in[7];
    const float* wl    = (const float*)d_in[8];
    const float* bls   = (const float*)d_in[9];
    const float* wr    = (const float*)d_in[10];
    const float* bn2g  = (const float*)d_in[11];
    const float* bn2b  = (const float*)d_in[12];
    const float* wg    = (const float*)d_in[13];
    const float* bg    = (const float*)d_in[14];

    const int N = in_sizes[0] / H;
    const int E = in_sizes[1] / 2;
    const int* src = ei;
    const int* dst = ei + E;
    float* outp = (float*)d_out;

    const int NRANGE = (N + RSIZE - 1) >> RBITS;     // 13 for N=100000

    u16* P0   = (u16*)d_ws;
    u16* P1   = P0 + (size_t)N * H;
    u16* P2   = P1 + (size_t)N * H;
    u16* xwsp = P2 + (size_t)N * H;              // N*64 bf16 (128B rows, padded)
    float* dinv = (float*)(xwsp + (size_t)N * 64);
    float* st   = dinv + N;
    int*  deg   = (int*)(st + 1024);
    int*  cursor= deg + N;
    int*  bsum  = cursor + N;
    int*  csr   = bsum + 1024;
    u16* wt1 = (u16*)(csr + E);
    u16* wt2 = wt1 + 16384;
    u16* wtl = wt2 + 16384;
    u16* wtr = wtl + 16384;
    u32* partial = (u32*)P0;                     // NRANGE*NB*16KB = 26MB over P0/P1
    float* sum1 = st,        *sumsq1 = st + 128;
    float* sum2 = st + 256,  *sumsq2 = st + 384;
    float* scale1 = st + 512, *shift1 = st + 640;
    float* scale2 = st + 768, *shift2 = st + 896;

    hipMemsetAsync(st, 0, 1024 * sizeof(float), stream);

    const int nb = (N + 1023) / 1024;
    const int total8 = N * H / 8;
    const int csrblk = NRANGE * NB;              // 1664 blocks

    k_prep<<<256, 256, 0, stream>>>(w1, w2, wl, wr, wt1, wt2, wtl, wtr);
    k_hist2<<<csrblk, 256, 0, stream>>>(dst, partial, E);
    k_scan1<<<nb, 256, 0, stream>>>(partial, deg, cursor, bsum, N);
    k_scan2<<<1, 256, 0, stream>>>(bsum, nb);
    k_scan3<<<(N + 255) / 256, 256, 0, stream>>>(cursor, bsum, deg, dinv, N);
    k_fill2<<<csrblk, 256, 0, stream>>>(src, dst, cursor, partial, csr, E);

    k_xbf<<<(total8 + 255) / 256, 256, 0, stream>>>(x, P2, total8);

    const int aggblk4 = (N + 15) / 16;
    const int gblocks = (N + 127) / 128;

    // ---- layer 1 ----
    k_agg1<<<aggblk4, 256, 0, stream>>>(P2, csr, cursor, deg, P0, N);
    k_gemm_film<<<gblocks, 512, 0, stream>>>(P0, wt1, b1, wt2, b2, P2, sum1, sumsq1, N);
    k_bnparams<<<1, 128, 0, stream>>>(sum1, sumsq1, bn1g, bn1b, scale1, shift1, 1.0f / N);

    // ---- layer 2 ----
    k_act1<<<(total8 + 255) / 256, 256, 0, stream>>>(P2, scale1, shift1, P0, total8);
    k_agg2<<<aggblk4, 256, 0, stream>>>(P0, csr, cursor, deg, P1, N);
    k_gemm_sage<<<gblocks, 512, 0, stream>>>(P1, P0, wtl, wtr, bls, P1, sum2, sumsq2, N);
    k_bnparams<<<1, 128, 0, stream>>>(sum2, sumsq2, bn2g, bn2b, scale2, shift2, 1.0f / N);

    // ---- layer 3 ----
    k_gcn<<<(N + 31) / 32, 320, 0, stream>>>(P1, scale2, shift2, wg, dinv, xwsp, N);
    k_agg3<<<aggblk4, 256, 0, stream>>>(xwsp, dinv, csr, cursor, deg, bg, outp, N);
}

// Round 18
// 393.434 us; speedup vs baseline: 1.1064x; 1.0004x over previous
//
#include <hip/hip_runtime.h>
#include <math.h>

#define H 128
#define OUTD 40
#define BN_EPS 1e-5f
#define NEG_SLOPE 0.01f
#define BUKW 128          // nodes per bucket
#define NC 256            // edge chunks for bucket sort
#define NBUKP 784         // padded bucket count (>= ceil(N/128))

typedef __attribute__((ext_vector_type(8))) short bh8;
typedef __attribute__((ext_vector_type(4))) float f4;
typedef unsigned short u16;
typedef unsigned int u32;

__device__ __forceinline__ float4 ld4(const float* p) {
    return *reinterpret_cast<const float4*>(p);
}
__device__ __forceinline__ u16 f2bf(float f) {
    unsigned int u = __float_as_uint(f);
    u += 0x7fffu + ((u >> 16) & 1u);          // RNE
    return (u16)(u >> 16);
}
__device__ __forceinline__ float bflo(unsigned d) { return __uint_as_float(d << 16); }
__device__ __forceinline__ float bfhi(unsigned d) { return __uint_as_float(d & 0xffff0000u); }
__device__ __forceinline__ unsigned pk(float a, float b) {
    return (unsigned)f2bf(a) | ((unsigned)f2bf(b) << 16);
}
__device__ __forceinline__ int swz(int row, int byteInRow) {
    return row * 256 + (byteInRow ^ ((row & 7) << 4));
}

// ================= x -> bf16 =================
__global__ __launch_bounds__(256) void k_xbf(
    const float* __restrict__ x, u16* __restrict__ xb, int total8)
{
    int i = blockIdx.x * 256 + threadIdx.x;
    if (i >= total8) return;
    float4 a = ld4(x + (size_t)i * 8);
    float4 b = ld4(x + (size_t)i * 8 + 4);
    uint4 o;
    o.x = pk(a.x, a.y); o.y = pk(a.z, a.w);
    o.z = pk(b.x, b.y); o.w = pk(b.z, b.w);
    *reinterpret_cast<uint4*>(xb + (size_t)i * 8) = o;
}

// ================= weight prep: WT[c][k] = bf16(W[k][c]) =================
__global__ __launch_bounds__(256) void k_prep(
    const float* __restrict__ w1, const float* __restrict__ w2,
    const float* __restrict__ wl, const float* __restrict__ wr,
    u16* __restrict__ wt1, u16* __restrict__ wt2,
    u16* __restrict__ wtl, u16* __restrict__ wtr)
{
    int id = blockIdx.x * 256 + threadIdx.x;
    int sel = id >> 14;
    int o = id & 16383;
    int c = o >> 7, k = o & 127;
    const float* w = (sel == 0) ? w1 : (sel == 1) ? w2 : (sel == 2) ? wl : wr;
    u16* wt = (sel == 0) ? wt1 : (sel == 1) ? wt2 : (sel == 2) ? wtl : wtr;
    wt[o] = f2bf(w[k * H + c]);
}

// ================= CSR build: bucket sort by 128-node windows =================
// A1: count per (chunk, bucket)
__global__ __launch_bounds__(512) void k_bcount(
    const int* __restrict__ dst, u32* __restrict__ counts, int E, int nbuk)
{
    __shared__ u32 cnt[NBUKP];
    const int tid = threadIdx.x;
    for (int t = tid; t < NBUKP; t += 512) cnt[t] = 0;
    __syncthreads();
    const int chunk = (E + NC - 1) / NC;
    const int s0 = blockIdx.x * chunk;
    const int s1 = min(E, s0 + chunk);
    for (int e = s0 + tid; e < s1; e += 512)
        atomicAdd(&cnt[(unsigned)dst[e] >> 7], 1u);
    __syncthreads();
    u32* out = counts + (size_t)blockIdx.x * NBUKP;
    for (int t = tid; t < nbuk; t += 512) out[t] = cnt[t];
}

// A2a: per-bucket: rewrite counts to exclusive chunk-prefix; total -> bukTot
__global__ __launch_bounds__(256) void k_bscan1(
    u32* __restrict__ counts, u32* __restrict__ bukTot, int nbuk)
{
    int b = blockIdx.x * 256 + threadIdx.x;
    if (b >= nbuk) return;
    u32 acc = 0;
    for (int c = 0; c < NC; c++) {
        u32* p = counts + (size_t)c * NBUKP + b;
        u32 v = *p;
        *p = acc;
        acc += v;
    }
    bukTot[b] = acc;
}

// A2b: exclusive scan of bukTot -> bukBase (single block)
__global__ void k_bscan2(const u32* __restrict__ bukTot, u32* __restrict__ bukBase, int nbuk)
{
    __shared__ u32 s[NBUKP];
    const int tid = threadIdx.x;
    for (int i = tid; i < nbuk; i += blockDim.x) s[i] = bukTot[i];
    __syncthreads();
    if (tid == 0) {
        u32 acc = 0;
        for (int i = 0; i < nbuk; i++) { u32 t = s[i]; s[i] = acc; acc += t; }
    }
    __syncthreads();
    for (int i = tid; i < nbuk; i += blockDim.x) bukBase[i] = s[i];
}

// A3: scatter (src,dst) into bucketed edge arrays
__global__ __launch_bounds__(512) void k_bscatter(
    const int* __restrict__ src, const int* __restrict__ dst,
    const u32* __restrict__ counts, const u32* __restrict__ bukBase,
    u32* __restrict__ esrc, u32* __restrict__ edst, int E)
{
    __shared__ u32 rk[NBUKP];
    const int tid = threadIdx.x;
    for (int t = tid; t < NBUKP; t += 512) rk[t] = 0;
    __syncthreads();
    const int chunk = (E + NC - 1) / NC;
    const int s0 = blockIdx.x * chunk;
    const int s1 = min(E, s0 + chunk);
    const u32* pref = counts + (size_t)blockIdx.x * NBUKP;
    for (int e = s0 + tid; e < s1; e += 512) {
        int d = dst[e];
        unsigned b = (unsigned)d >> 7;
        u32 r = atomicAdd(&rk[b], 1u);
        u32 pos = bukBase[b] + pref[b] + r;
        esrc[pos] = (u32)src[e];
        edst[pos] = (u32)d;
    }
}

// B1: per-bucket node degree (clean 512B stores)
__global__ __launch_bounds__(256) void k_bdeg(
    const u32* __restrict__ edst, const u32* __restrict__ bukBase,
    const u32* __restrict__ bukTot, int* __restrict__ deg, int n)
{
    __shared__ u32 dcnt[BUKW];
    const int tid = threadIdx.x;
    const int b = blockIdx.x;
    if (tid < BUKW) dcnt[tid] = 0;
    __syncthreads();
    const u32 s0 = bukBase[b];
    const u32 s1 = s0 + bukTot[b];
    for (u32 e = s0 + tid; e < s1; e += 256)
        atomicAdd(&dcnt[edst[e] & (BUKW - 1)], 1u);
    __syncthreads();
    if (tid < BUKW) {
        int node = b * BUKW + tid;
        if (node < n) deg[node] = (int)dcnt[tid];
    }
}

// plain N-scan of deg -> cursor (block-local, 1024/block) + bsum
__global__ __launch_bounds__(256) void k_scan1n(
    const int* __restrict__ deg, int* __restrict__ cursor, int* __restrict__ bsum, int n)
{
    __shared__ int sums[256];
    const int tid = threadIdx.x;
    const int idx = blockIdx.x * 1024 + tid * 4;
    int4 v = {0, 0, 0, 0};
    if (idx + 3 < n) v = *reinterpret_cast<const int4*>(deg + idx);
    else {
        if (idx + 0 < n) v.x = deg[idx + 0];
        if (idx + 1 < n) v.y = deg[idx + 1];
        if (idx + 2 < n) v.z = deg[idx + 2];
        if (idx + 3 < n) v.w = deg[idx + 3];
    }
    int t = v.x + v.y + v.z + v.w;
    sums[tid] = t;
    __syncthreads();
    for (int off = 1; off < 256; off <<= 1) {
        int other = (tid >= off) ? sums[tid - off] : 0;
        __syncthreads();
        sums[tid] += other;
        __syncthreads();
    }
    int incl = sums[tid];
    int excl = incl - t;
    if (tid == 255) bsum[blockIdx.x] = incl;
    int c0 = excl, c1 = c0 + v.x, c2 = c1 + v.y, c3 = c2 + v.z;
    if (idx + 3 < n) {
        int4 o = {c0, c1, c2, c3};
        *reinterpret_cast<int4*>(cursor + idx) = o;
    } else {
        if (idx + 0 < n) cursor[idx + 0] = c0;
        if (idx + 1 < n) cursor[idx + 1] = c1;
        if (idx + 2 < n) cursor[idx + 2] = c2;
        if (idx + 3 < n) cursor[idx + 3] = c3;
    }
}

__global__ void k_scan2(int* __restrict__ bsum, int nb)
{
    __shared__ int s[1024];
    const int tid = threadIdx.x;
    for (int i = tid; i < nb; i += blockDim.x) s[i] = bsum[i];
    __syncthreads();
    if (tid == 0) {
        int acc = 0;
        for (int i = 0; i < nb; i++) { int t = s[i]; s[i] = acc; acc += t; }
    }
    __syncthreads();
    for (int i = tid; i < nb; i += blockDim.x) bsum[i] = s[i];
}

__global__ __launch_bounds__(256) void k_scan3(
    int* __restrict__ cursor, const int* __restrict__ bsum,
    const int* __restrict__ deg, float* __restrict__ dinv, int n)
{
    int i = blockIdx.x * 256 + threadIdx.x;
    if (i < n) {
        cursor[i] += bsum[i >> 10];
        dinv[i] = rsqrtf((float)deg[i] + 1.0f);
    }
}

// B2: fill csr; bucket's csr window is single-writer -> line-dense stores
__global__ __launch_bounds__(256) void k_bfill(
    const u32* __restrict__ esrc, const u32* __restrict__ edst,
    const u32* __restrict__ bukBase, const u32* __restrict__ bukTot,
    const int* __restrict__ cursor, int* __restrict__ csr, int n)
{
    __shared__ int lcur[BUKW];
    const int tid = threadIdx.x;
    const int b = blockIdx.x;
    if (tid < BUKW) {
        int node = b * BUKW + tid;
        lcur[tid] = (node < n) ? cursor[node] : 0;
    }
    __syncthreads();
    const u32 s0 = bukBase[b];
    const u32 s1 = s0 + bukTot[b];
    for (u32 e = s0 + tid; e < s1; e += 256) {
        int dl = (int)(edst[e] & (BUKW - 1));
        int slot = atomicAdd(&lcur[dl], 1);
        csr[slot] = (int)esrc[e];
    }
}

// ================= gather aggregations (bf16 features) =================
__global__ __launch_bounds__(256) void k_agg1(
    const u16* __restrict__ xb, const int* __restrict__ csr,
    const int* __restrict__ cursor, const int* __restrict__ deg,
    u16* __restrict__ out, int n)
{
    int wave = (blockIdx.x * 256 + threadIdx.x) >> 6;
    int lane = threadIdx.x & 63;
    int row = wave * 4 + (lane >> 4);
    if (row >= n) return;
    int g = lane & 15;
    int start = cursor[row];
    int end = start + deg[row];
    float acc[8] = {0.f, 0.f, 0.f, 0.f, 0.f, 0.f, 0.f, 0.f};
    int i = start;
    for (; i + 4 <= end; i += 4) {
        int s0 = csr[i], s1 = csr[i + 1], s2 = csr[i + 2], s3 = csr[i + 3];
        uint4 a = *reinterpret_cast<const uint4*>(xb + (size_t)s0 * H + g * 8);
        uint4 b = *reinterpret_cast<const uint4*>(xb + (size_t)s1 * H + g * 8);
        uint4 c = *reinterpret_cast<const uint4*>(xb + (size_t)s2 * H + g * 8);
        uint4 d = *reinterpret_cast<const uint4*>(xb + (size_t)s3 * H + g * 8);
        acc[0] += (bflo(a.x) + bflo(b.x)) + (bflo(c.x) + bflo(d.x));
        acc[1] += (bfhi(a.x) + bfhi(b.x)) + (bfhi(c.x) + bfhi(d.x));
        acc[2] += (bflo(a.y) + bflo(b.y)) + (bflo(c.y) + bflo(d.y));
        acc[3] += (bfhi(a.y) + bfhi(b.y)) + (bfhi(c.y) + bfhi(d.y));
        acc[4] += (bflo(a.z) + bflo(b.z)) + (bflo(c.z) + bflo(d.z));
        acc[5] += (bfhi(a.z) + bfhi(b.z)) + (bfhi(c.z) + bfhi(d.z));
        acc[6] += (bflo(a.w) + bflo(b.w)) + (bflo(c.w) + bflo(d.w));
        acc[7] += (bfhi(a.w) + bfhi(b.w)) + (bfhi(c.w) + bfhi(d.w));
    }
    for (; i < end; i++) {
        int s = csr[i];
        uint4 a = *reinterpret_cast<const uint4*>(xb + (size_t)s * H + g * 8);
        acc[0] += bflo(a.x); acc[1] += bfhi(a.x);
        acc[2] += bflo(a.y); acc[3] += bfhi(a.y);
        acc[4] += bflo(a.z); acc[5] += bfhi(a.z);
        acc[6] += bflo(a.w); acc[7] += bfhi(a.w);
    }
    uint4 o;
    o.x = pk(acc[0], acc[1]); o.y = pk(acc[2], acc[3]);
    o.z = pk(acc[4], acc[5]); o.w = pk(acc[6], acc[7]);
    *reinterpret_cast<uint4*>(out + (size_t)row * H + g * 8) = o;
}

// act1h = bf16(relu(affine1(h))), elementwise
__global__ __launch_bounds__(256) void k_act1(
    const u16* __restrict__ hb, const float* __restrict__ scale, const float* __restrict__ shift,
    u16* __restrict__ out, int total8)
{
    int i = blockIdx.x * 256 + threadIdx.x;
    if (i >= total8) return;
    int g = i & 15;
    uint4 a = *reinterpret_cast<const uint4*>(hb + (size_t)i * 8);
    float4 sc0 = ld4(scale + g * 8), sc1 = ld4(scale + g * 8 + 4);
    float4 sh0 = ld4(shift + g * 8), sh1 = ld4(shift + g * 8 + 4);
    float e0 = fmaxf(bflo(a.x) * sc0.x + sh0.x, 0.f);
    float e1 = fmaxf(bfhi(a.x) * sc0.y + sh0.y, 0.f);
    float e2 = fmaxf(bflo(a.y) * sc0.z + sh0.z, 0.f);
    float e3 = fmaxf(bfhi(a.y) * sc0.w + sh0.w, 0.f);
    float e4 = fmaxf(bflo(a.z) * sc1.x + sh1.x, 0.f);
    float e5 = fmaxf(bfhi(a.z) * sc1.y + sh1.y, 0.f);
    float e6 = fmaxf(bflo(a.w) * sc1.z + sh1.z, 0.f);
    float e7 = fmaxf(bfhi(a.w) * sc1.w + sh1.w, 0.f);
    uint4 o;
    o.x = pk(e0, e1); o.y = pk(e2, e3); o.z = pk(e4, e5); o.w = pk(e6, e7);
    *reinterpret_cast<uint4*>(out + (size_t)i * 8) = o;
}

__global__ __launch_bounds__(256) void k_agg2(
    const u16* __restrict__ ab, const int* __restrict__ csr,
    const int* __restrict__ cursor, const int* __restrict__ deg,
    u16* __restrict__ out, int n)
{
    int wave = (blockIdx.x * 256 + threadIdx.x) >> 6;
    int lane = threadIdx.x & 63;
    int row = wave * 4 + (lane >> 4);
    if (row >= n) return;
    int g = lane & 15;
    int dg = deg[row];
    int start = cursor[row];
    int end = start + dg;
    float acc[8] = {0.f, 0.f, 0.f, 0.f, 0.f, 0.f, 0.f, 0.f};
    int i = start;
    for (; i + 4 <= end; i += 4) {
        int s0 = csr[i], s1 = csr[i + 1], s2 = csr[i + 2], s3 = csr[i + 3];
        uint4 a = *reinterpret_cast<const uint4*>(ab + (size_t)s0 * H + g * 8);
        uint4 b = *reinterpret_cast<const uint4*>(ab + (size_t)s1 * H + g * 8);
        uint4 c = *reinterpret_cast<const uint4*>(ab + (size_t)s2 * H + g * 8);
        uint4 d = *reinterpret_cast<const uint4*>(ab + (size_t)s3 * H + g * 8);
        acc[0] += (bflo(a.x) + bflo(b.x)) + (bflo(c.x) + bflo(d.x));
        acc[1] += (bfhi(a.x) + bfhi(b.x)) + (bfhi(c.x) + bfhi(d.x));
        acc[2] += (bflo(a.y) + bflo(b.y)) + (bflo(c.y) + bflo(d.y));
        acc[3] += (bfhi(a.y) + bfhi(b.y)) + (bfhi(c.y) + bfhi(d.y));
        acc[4] += (bflo(a.z) + bflo(b.z)) + (bflo(c.z) + bflo(d.z));
        acc[5] += (bfhi(a.z) + bfhi(b.z)) + (bfhi(c.z) + bfhi(d.z));
        acc[6] += (bflo(a.w) + bflo(b.w)) + (bflo(c.w) + bflo(d.w));
        acc[7] += (bfhi(a.w) + bfhi(b.w)) + (bfhi(c.w) + bfhi(d.w));
    }
    for (; i < end; i++) {
        int s = csr[i];
        uint4 a = *reinterpret_cast<const uint4*>(ab + (size_t)s * H + g * 8);
        acc[0] += bflo(a.x); acc[1] += bfhi(a.x);
        acc[2] += bflo(a.y); acc[3] += bfhi(a.y);
        acc[4] += bflo(a.z); acc[5] += bfhi(a.z);
        acc[6] += bflo(a.w); acc[7] += bfhi(a.w);
    }
    float idv = 1.0f / fmaxf((float)dg, 1.0f);
    uint4 o;
    o.x = pk(acc[0] * idv, acc[1] * idv); o.y = pk(acc[2] * idv, acc[3] * idv);
    o.z = pk(acc[4] * idv, acc[5] * idv); o.w = pk(acc[6] * idv, acc[7] * idv);
    *reinterpret_cast<uint4*>(out + (size_t)row * H + g * 8) = o;
}

// GCN gather + self-loop + bias + log-softmax; xwsp[N][64] padded
__global__ __launch_bounds__(256) void k_agg3(
    const u16* __restrict__ xwsp, const float* __restrict__ dinv,
    const int* __restrict__ csr, const int* __restrict__ cursor, const int* __restrict__ deg,
    const float* __restrict__ bias, float* __restrict__ outp, int n)
{
    int wave = (blockIdx.x * 256 + threadIdx.x) >> 6;
    int lane = threadIdx.x & 63;
    int row = wave * 4 + (lane >> 4);
    if (row >= n) return;
    int g = lane & 15;
    bool act = g < 10;
    const u16* base = xwsp + g * 4;
    int start = cursor[row];
    int end = start + deg[row];
    float a0 = 0.f, a1 = 0.f, a2 = 0.f, a3 = 0.f;
    int i = start;
    for (; i + 4 <= end; i += 4) {
        int s0 = csr[i], s1 = csr[i + 1], s2 = csr[i + 2], s3 = csr[i + 3];
        uint2 u0 = *reinterpret_cast<const uint2*>(base + (size_t)s0 * 64);
        uint2 u1 = *reinterpret_cast<const uint2*>(base + (size_t)s1 * 64);
        uint2 u2 = *reinterpret_cast<const uint2*>(base + (size_t)s2 * 64);
        uint2 u3 = *reinterpret_cast<const uint2*>(base + (size_t)s3 * 64);
        a0 += (bflo(u0.x) + bflo(u1.x)) + (bflo(u2.x) + bflo(u3.x));
        a1 += (bfhi(u0.x) + bfhi(u1.x)) + (bfhi(u2.x) + bfhi(u3.x));
        a2 += (bflo(u0.y) + bflo(u1.y)) + (bflo(u2.y) + bflo(u3.y));
        a3 += (bfhi(u0.y) + bfhi(u1.y)) + (bfhi(u2.y) + bfhi(u3.y));
    }
    for (; i < end; i++) {
        uint2 u = *reinterpret_cast<const uint2*>(base + (size_t)csr[i] * 64);
        a0 += bflo(u.x); a1 += bfhi(u.x);
        a2 += bflo(u.y); a3 += bfhi(u.y);
    }
    uint2 sf = *reinterpret_cast<const uint2*>(base + (size_t)row * 64);
    float di = dinv[row];
    float4 bb = {0.f, 0.f, 0.f, 0.f};
    if (act) bb = ld4(bias + g * 4);
    float v0 = di * (a0 + bflo(sf.x)) + bb.x;
    float v1 = di * (a1 + bfhi(sf.x)) + bb.y;
    float v2 = di * (a2 + bflo(sf.y)) + bb.z;
    float v3 = di * (a3 + bfhi(sf.y)) + bb.w;
    float m = act ? fmaxf(fmaxf(v0, v1), fmaxf(v2, v3)) : -INFINITY;
#pragma unroll
    for (int s = 1; s < 16; s <<= 1) m = fmaxf(m, __shfl_xor(m, s, 64));
    float e0 = act ? expf(v0 - m) : 0.f;
    float e1 = act ? expf(v1 - m) : 0.f;
    float e2 = act ? expf(v2 - m) : 0.f;
    float e3 = act ? expf(v3 - m) : 0.f;
    float sum = (e0 + e1) + (e2 + e3);
#pragma unroll
    for (int s = 1; s < 16; s <<= 1) sum += __shfl_xor(sum, s, 64);
    float l = logf(sum) + m;
    if (act) {
        float4 o = {v0 - l, v1 - l, v2 - l, v3 - l};
        *reinterpret_cast<float4*>(outp + (size_t)row * OUTD + g * 4) = o;
    }
}

// ================= MFMA dense layers (128-row tiles, 512 threads) =================
__global__ __launch_bounds__(512) void k_gemm_film(
    const u16* __restrict__ A, const u16* __restrict__ W1T, const float* __restrict__ b1,
    const u16* __restrict__ W2T, const float* __restrict__ b2,
    u16* __restrict__ out, float* __restrict__ gsum, float* __restrict__ gsumsq, int n)
{
    __shared__ u16 sA[128 * 128];
    __shared__ u16 sB[128 * 128];
    __shared__ float cs[128], css[128];
    const int tid = threadIdx.x;
    const int rb = blockIdx.x * 128;
    if (tid < 128) { cs[tid] = 0.f; css[tid] = 0.f; }
    const int w = tid >> 6, l15 = tid & 15, grp = (tid & 63) >> 4;

#pragma unroll
    for (int j = 0; j < 4; j++) {
        int f = j * 512 + tid;
        int r = f >> 4, g = f & 15;
        int row = rb + r;
        uint4 v = {0, 0, 0, 0};
        if (row < n) v = *reinterpret_cast<const uint4*>(A + (size_t)row * H + g * 8);
        *reinterpret_cast<uint4*>((char*)sA + swz(r, g * 16)) = v;
    }
#pragma unroll
    for (int j = 0; j < 4; j++) {
        int f = j * 512 + tid;
        int r = f >> 4, kb = f & 15;
        uint4 v = *reinterpret_cast<const uint4*>(W1T + r * H + kb * 8);
        *reinterpret_cast<uint4*>((char*)sB + swz(r, kb * 16)) = v;
    }
    __syncthreads();
    f4 acc[8] = {};
#pragma unroll
    for (int kc = 0; kc < 4; kc++) {
        bh8 af = *reinterpret_cast<const bh8*>((char*)sA + swz(w * 16 + l15, kc * 64 + grp * 16));
#pragma unroll
        for (int nf = 0; nf < 8; nf++) {
            bh8 bv = *reinterpret_cast<const bh8*>((char*)sB + swz(nf * 16 + l15, kc * 64 + grp * 16));
            acc[nf] = __builtin_amdgcn_mfma_f32_16x16x32_bf16(af, bv, acc[nf], 0, 0, 0);
        }
    }
    __syncthreads();

#pragma unroll
    for (int nf = 0; nf < 8; nf++) {
        int col = nf * 16 + l15;
        float bc = b1[col];
#pragma unroll
        for (int j = 0; j < 4; j++) {
            int row = w * 16 + grp * 4 + j;
            float u = acc[nf][j] + bc;
            u = u > 0.f ? u : NEG_SLOPE * u;
            *reinterpret_cast<u16*>((char*)sA + swz(row, col * 2)) = f2bf(u);
        }
        acc[nf] = f4{0.f, 0.f, 0.f, 0.f};
    }
#pragma unroll
    for (int j = 0; j < 4; j++) {
        int f = j * 512 + tid;
        int r = f >> 4, kb = f & 15;
        uint4 v = *reinterpret_cast<const uint4*>(W2T + r * H + kb * 8);
        *reinterpret_cast<uint4*>((char*)sB + swz(r, kb * 16)) = v;
    }
    __syncthreads();

#pragma unroll
    for (int kc = 0; kc < 4; kc++) {
        bh8 af = *reinterpret_cast<const bh8*>((char*)sA + swz(w * 16 + l15, kc * 64 + grp * 16));
#pragma unroll
        for (int nf = 0; nf < 8; nf++) {
            bh8 bv = *reinterpret_cast<const bh8*>((char*)sB + swz(nf * 16 + l15, kc * 64 + grp * 16));
            acc[nf] = __builtin_amdgcn_mfma_f32_16x16x32_bf16(af, bv, acc[nf], 0, 0, 0);
        }
    }

#pragma unroll
    for (int nf = 0; nf < 8; nf++) {
        float bc = b2[nf * 16 + l15];
#pragma unroll
        for (int j = 0; j < 4; j++) acc[nf][j] += bc;
    }
    float inv[4];
#pragma unroll
    for (int j = 0; j < 4; j++) {
        float ss = 0.f;
#pragma unroll
        for (int nf = 0; nf < 8; nf++) ss += acc[nf][j] * acc[nf][j];
        ss += __shfl_xor(ss, 1, 64); ss += __shfl_xor(ss, 2, 64);
        ss += __shfl_xor(ss, 4, 64); ss += __shfl_xor(ss, 8, 64);
        inv[j] = 1.0f / fmaxf(sqrtf(ss), 1e-12f);
    }
#pragma unroll
    for (int nf = 0; nf < 8; nf++) {
        int col = nf * 16 + l15;
        float s = 0.f, q = 0.f;
#pragma unroll
        for (int j = 0; j < 4; j++) {
            int row = rb + w * 16 + grp * 4 + j;
            float u = acc[nf][j] * inv[j];
            if (row < n) {
                out[(size_t)row * H + col] = f2bf(u);
                s += u; q += u * u;
            }
        }
        s += __shfl_xor(s, 16, 64); s += __shfl_xor(s, 32, 64);
        q += __shfl_xor(q, 16, 64); q += __shfl_xor(q, 32, 64);
        if (grp == 0) { atomicAdd(&cs[col], s); atomicAdd(&css[col], q); }
    }
    __syncthreads();
    if (tid < 128) { atomicAdd(gsum + tid, cs[tid]); atomicAdd(gsumsq + tid, css[tid]); }
}

__global__ __launch_bounds__(512) void k_gemm_sage(
    const u16* __restrict__ Am, const u16* __restrict__ Ab,
    const u16* __restrict__ WlT, const u16* __restrict__ WrT,
    const float* __restrict__ bl, u16* __restrict__ out,
    float* __restrict__ gsum, float* __restrict__ gsumsq, int n)
{
    __shared__ u16 sA[128 * 128];
    __shared__ u16 sB[128 * 128];
    __shared__ float cs[128], css[128];
    const int tid = threadIdx.x;
    const int rb = blockIdx.x * 128;
    if (tid < 128) { cs[tid] = 0.f; css[tid] = 0.f; }
    const int w = tid >> 6, l15 = tid & 15, grp = (tid & 63) >> 4;
    f4 acc[8] = {};

#pragma unroll
    for (int j = 0; j < 4; j++) {
        int f = j * 512 + tid;
        int r = f >> 4, g = f & 15;
        int row = rb + r;
        uint4 v = {0, 0, 0, 0};
        if (row < n) v = *reinterpret_cast<const uint4*>(Am + (size_t)row * H + g * 8);
        *reinterpret_cast<uint4*>((char*)sA + swz(r, g * 16)) = v;
    }
#pragma unroll
    for (int j = 0; j < 4; j++) {
        int f = j * 512 + tid;
        int r = f >> 4, kb = f & 15;
        uint4 v = *reinterpret_cast<const uint4*>(WlT + r * H + kb * 8);
        *reinterpret_cast<uint4*>((char*)sB + swz(r, kb * 16)) = v;
    }
    __syncthreads();
#pragma unroll
    for (int kc = 0; kc < 4; kc++) {
        bh8 af = *reinterpret_cast<const bh8*>((char*)sA + swz(w * 16 + l15, kc * 64 + grp * 16));
#pragma unroll
        for (int nf = 0; nf < 8; nf++) {
            bh8 bv = *reinterpret_cast<const bh8*>((char*)sB + swz(nf * 16 + l15, kc * 64 + grp * 16));
            acc[nf] = __builtin_amdgcn_mfma_f32_16x16x32_bf16(af, bv, acc[nf], 0, 0, 0);
        }
    }
    __syncthreads();

#pragma unroll
    for (int j = 0; j < 4; j++) {
        int f = j * 512 + tid;
        int r = f >> 4, g = f & 15;
        int row = rb + r;
        uint4 v = {0, 0, 0, 0};
        if (row < n) v = *reinterpret_cast<const uint4*>(Ab + (size_t)row * H + g * 8);
        *reinterpret_cast<uint4*>((char*)sA + swz(r, g * 16)) = v;
    }
#pragma unroll
    for (int j = 0; j < 4; j++) {
        int f = j * 512 + tid;
        int r = f >> 4, kb = f & 15;
        uint4 v = *reinterpret_cast<const uint4*>(WrT + r * H + kb * 8);
        *reinterpret_cast<uint4*>((char*)sB + swz(r, kb * 16)) = v;
    }
    __syncthreads();
#pragma unroll
    for (int kc = 0; kc < 4; kc++) {
        bh8 af = *reinterpret_cast<const bh8*>((char*)sA + swz(w * 16 + l15, kc * 64 + grp * 16));
#pragma unroll
        for (int nf = 0; nf < 8; nf++) {
            bh8 bv = *reinterpret_cast<const bh8*>((char*)sB + swz(nf * 16 + l15, kc * 64 + grp * 16));
            acc[nf] = __builtin_amdgcn_mfma_f32_16x16x32_bf16(af, bv, acc[nf], 0, 0, 0);
        }
    }

#pragma unroll
    for (int nf = 0; nf < 8; nf++) {
        int col = nf * 16 + l15;
        float bc = bl[col];
        float s = 0.f, q = 0.f;
#pragma unroll
        for (int j = 0; j < 4; j++) {
            int row = rb + w * 16 + grp * 4 + j;
            float u = acc[nf][j] + bc;
            if (row < n) {
                out[(size_t)row * H + col] = f2bf(u);
                s += u; q += u * u;
            }
        }
        s += __shfl_xor(s, 16, 64); s += __shfl_xor(s, 32, 64);
        q += __shfl_xor(q, 16, 64); q += __shfl_xor(q, 32, 64);
        if (grp == 0) { atomicAdd(&cs[col], s); atomicAdd(&css[col], q); }
    }
    __syncthreads();
    if (tid < 128) { atomicAdd(gsum + tid, cs[tid]); atomicAdd(gsumsq + tid, css[tid]); }
}

__global__ void k_bnparams(const float* __restrict__ gsum, const float* __restrict__ gsumsq,
                           const float* __restrict__ g, const float* __restrict__ b,
                           float* __restrict__ scale, float* __restrict__ shift, float inv_n)
{
    int c = threadIdx.x;
    float mu = gsum[c] * inv_n;
    float var = fmaxf(gsumsq[c] * inv_n - mu * mu, 0.f);
    float sc = g[c] * rsqrtf(var + BN_EPS);
    scale[c] = sc;
    shift[c] = b[c] - mu * sc;
}

// GCN dense: write xwsp[N][64] (dinv-prescaled bf16; cols 40..63 unwritten pad)
__global__ __launch_bounds__(320) void k_gcn(
    const u16* __restrict__ H2, const float* __restrict__ scale2, const float* __restrict__ shift2,
    const float* __restrict__ Wg, const float* __restrict__ dinv,
    u16* __restrict__ xwsp, int n)
{
    __shared__ float sW[H * OUTD];
    __shared__ float sA[32][H];
    const int tid = threadIdx.x;
#pragma unroll
    for (int j = 0; j < 4; j++) {
        int off = (tid + j * 320) * 4;
        *reinterpret_cast<float4*>(&sW[off]) = ld4(Wg + off);
    }
    const int rb = blockIdx.x * 32;
#pragma unroll
    for (int j = 0; j < 2; j++) {
        int li = tid + j * 320;
        if (li < 512) {
            int r = li >> 4, g = li & 15;
            int row = rb + r;
            float4 v0 = {0.f, 0.f, 0.f, 0.f}, v1 = {0.f, 0.f, 0.f, 0.f};
            if (row < n) {
                uint4 a = *reinterpret_cast<const uint4*>(H2 + (size_t)row * H + g * 8);
                float4 sc0 = ld4(scale2 + g * 8), sc1 = ld4(scale2 + g * 8 + 4);
                float4 sh0 = ld4(shift2 + g * 8), sh1 = ld4(shift2 + g * 8 + 4);
                v0.x = fmaxf(bflo(a.x) * sc0.x + sh0.x, 0.f);
                v0.y = fmaxf(bfhi(a.x) * sc0.y + sh0.y, 0.f);
                v0.z = fmaxf(bflo(a.y) * sc0.z + sh0.z, 0.f);
                v0.w = fmaxf(bfhi(a.y) * sc0.w + sh0.w, 0.f);
                v1.x = fmaxf(bflo(a.z) * sc1.x + sh1.x, 0.f);
                v1.y = fmaxf(bfhi(a.z) * sc1.y + sh1.y, 0.f);
                v1.z = fmaxf(bflo(a.w) * sc1.z + sh1.z, 0.f);
                v1.w = fmaxf(bfhi(a.w) * sc1.w + sh1.w, 0.f);
            }
            *reinterpret_cast<float4*>(&sA[r][g * 8]) = v0;
            *reinterpret_cast<float4*>(&sA[r][g * 8 + 4]) = v1;
        }
    }
    __syncthreads();
    const int c = tid % OUTD;
    const int rg = tid / OUTD;
    float acc[4] = {0.f, 0.f, 0.f, 0.f};
    for (int k = 0; k < H; k++) {
        float w = sW[k * OUTD + c];
#pragma unroll
        for (int i = 0; i < 4; i++) acc[i] += sA[rg + i * 8][k] * w;
    }
#pragma unroll
    for (int i = 0; i < 4; i++) {
        int row = rb + rg + i * 8;
        if (row < n) xwsp[(size_t)row * 64 + c] = f2bf(dinv[row] * acc[i]);
    }
}

extern "C" void kernel_launch(void* const* d_in, const int* in_sizes, int n_in,
                              void* d_out, int out_size, void* d_ws, size_t ws_size,
                              hipStream_t stream)
{
    const float* x     = (const float*)d_in[0];
    const int*   ei    = (const int*)d_in[1];
    const float* w1    = (const float*)d_in[2];
    const float* b1    = (const float*)d_in[3];
    const float* w2    = (const float*)d_in[4];
    const float* b2    = (const float*)d_in[5];
    const float* bn1g  = (const float*)d_in[6];
    const float* bn1b  = (const float*)d_in[7];
    const float* wl    = (const float*)d_in[8];
    const float* bls   = (const float*)d_in[9];
    const float* wr    = (const float*)d_in[10];
    const float* bn2g  = (const float*)d_in[11];
    const float* bn2b  = (const float*)d_in[12];
    const float* wg    = (const float*)d_in[13];
    const float* bg    = (const float*)d_in[14];

    const int N = in_sizes[0] / H;
    const int E = in_sizes[1] / 2;
    const int* src = ei;
    const int* dst = ei + E;
    float* outp = (float*)d_out;

    const int NBUK = (N + BUKW - 1) / BUKW;      // 782 for N=100000

    u16* P0   = (u16*)d_ws;
    u16* P1   = P0 + (size_t)N * H;
    u16* P2   = P1 + (size_t)N * H;
    u16* xwsp = P2 + (size_t)N * H;              // N*64 bf16 (128B rows, padded)
    float* dinv = (float*)(xwsp + (size_t)N * 64);
    float* st   = dinv + N;
    int*  deg   = (int*)(st + 1024);
    int*  cursor= deg + N;
    int*  bsum  = cursor + N;
    int*  csr   = bsum + 1024;
    u16* wt1 = (u16*)(csr + E);
    u16* wt2 = wt1 + 16384;
    u16* wtl = wt2 + 16384;
    u16* wtr = wtl + 16384;
    // bucket-sort scratch aliases P0/P1 (dead before agg1 writes P0)
    u32* counts  = (u32*)P0;                     // NC*NBUKP = 803KB
    u32* bukTot  = counts + (size_t)NC * NBUKP;  // NBUKP
    u32* bukBase = bukTot + NBUKP;               // NBUKP
    u32* esrc    = bukBase + NBUKP;              // E
    u32* edst    = esrc + E;                     // E
    float* sum1 = st,        *sumsq1 = st + 128;
    float* sum2 = st + 256,  *sumsq2 = st + 384;
    float* scale1 = st + 512, *shift1 = st + 640;
    float* scale2 = st + 768, *shift2 = st + 896;

    hipMemsetAsync(st, 0, 1024 * sizeof(float), stream);

    const int nb = (N + 1023) / 1024;
    const int total8 = N * H / 8;

    k_prep<<<256, 256, 0, stream>>>(w1, w2, wl, wr, wt1, wt2, wtl, wtr);

    // ---- CSR build: bucket sort ----
    k_bcount<<<NC, 512, 0, stream>>>(dst, counts, E, NBUK);
    k_bscan1<<<(NBUK + 255) / 256, 256, 0, stream>>>(counts, bukTot, NBUK);
    k_bscan2<<<1, 256, 0, stream>>>(bukTot, bukBase, NBUK);
    k_bscatter<<<NC, 512, 0, stream>>>(src, dst, counts, bukBase, esrc, edst, E);
    k_bdeg<<<NBUK, 256, 0, stream>>>(edst, bukBase, bukTot, deg, N);
    k_scan1n<<<nb, 256, 0, stream>>>(deg, cursor, bsum, N);
    k_scan2<<<1, 256, 0, stream>>>(bsum, nb);
    k_scan3<<<(N + 255) / 256, 256, 0, stream>>>(cursor, bsum, deg, dinv, N);
    k_bfill<<<NBUK, 256, 0, stream>>>(esrc, edst, bukBase, bukTot, cursor, csr, N);

    k_xbf<<<(total8 + 255) / 256, 256, 0, stream>>>(x, P2, total8);

    const int aggblk4 = (N + 15) / 16;
    const int gblocks = (N + 127) / 128;

    // ---- layer 1 ----
    k_agg1<<<aggblk4, 256, 0, stream>>>(P2, csr, cursor, deg, P0, N);
    k_gemm_film<<<gblocks, 512, 0, stream>>>(P0, wt1, b1, wt2, b2, P2, sum1, sumsq1, N);
    k_bnparams<<<1, 128, 0, stream>>>(sum1, sumsq1, bn1g, bn1b, scale1, shift1, 1.0f / N);

    // ---- layer 2 ----
    k_act1<<<(total8 + 255) / 256, 256, 0, stream>>>(P2, scale1, shift1, P0, total8);
    k_agg2<<<aggblk4, 256, 0, stream>>>(P0, csr, cursor, deg, P1, N);
    k_gemm_sage<<<gblocks, 512, 0, stream>>>(P1, P0, wtl, wtr, bls, P1, sum2, sumsq2, N);
    k_bnparams<<<1, 128, 0, stream>>>(sum2, sumsq2, bn2g, bn2b, scale2, shift2, 1.0f / N);

    // ---- layer 3 ----
    k_gcn<<<(N + 31) / 32, 320, 0, stream>>>(P1, scale2, shift2, wg, dinv, xwsp, N);
    k_agg3<<<aggblk4, 256, 0, stream>>>(xwsp, dinv, csr, cursor, deg, bg, outp, N);
}